// Round 11
// baseline (254.630 us; speedup 1.0000x reference)
//
#include <hip/hip_runtime.h>
#include <hip/hip_bf16.h>
#include <stdint.h>

// Problem constants: B=4, S=2048, D=1024, H=16, HD=64, M = B*S = 8192.

typedef unsigned short ushortT;
typedef __attribute__((ext_vector_type(8))) __bf16 bf16x8;
typedef __attribute__((ext_vector_type(4))) float f32x4;
typedef __attribute__((ext_vector_type(16))) float f32x16;
typedef __attribute__((ext_vector_type(8))) unsigned short ushort8;
typedef __attribute__((ext_vector_type(4))) unsigned short ushort4v;

__device__ __forceinline__ unsigned short f2bf(float f) {
  union { float f; unsigned u; } x; x.f = f;
  unsigned r = (x.u + 0x7FFFu + ((x.u >> 16) & 1u)) >> 16;  // RNE
  return (unsigned short)r;
}

// packed f32x2 -> bf16x2 (RNE), dst[15:0]=lo, dst[31:16]=hi
__device__ __forceinline__ unsigned cvtpk_bf16(float lo, float hi) {
  unsigned r;
  asm("v_cvt_pk_bf16_f32 %0, %1, %2" : "=v"(r) : "v"(lo), "v"(hi));
  return r;
}

__device__ __forceinline__ void load_lds16(const void* g, void* l) {
  __builtin_amdgcn_global_load_lds(
      (const __attribute__((address_space(1))) void*)g,
      (__attribute__((address_space(3))) void*)l, 16, 0, 0);
}

__device__ __forceinline__ f32x4 mfma16(bf16x8 a, bf16x8 b, f32x4 c) {
  return __builtin_amdgcn_mfma_f32_16x16x32_bf16(a, b, c, 0, 0, 0);
}
__device__ __forceinline__ f32x16 mfma32(bf16x8 a, bf16x8 b, f32x16 c) {
  return __builtin_amdgcn_mfma_f32_32x32x16_bf16(a, b, c, 0, 0, 0);
}

// ---------------- f32 -> bf16 convert, all 6 tensors in one launch ---------
__global__ __launch_bounds__(256) void k_cvt_all(
    const float* __restrict__ x, const float* __restrict__ y,
    const float* __restrict__ w0, const float* __restrict__ w1,
    const float* __restrict__ w2, const float* __restrict__ w3,
    ushortT* __restrict__ ox, ushortT* __restrict__ oy,
    ushortT* __restrict__ o0, ushortT* __restrict__ o1,
    ushortT* __restrict__ o2, ushortT* __restrict__ o3) {
  int b = blockIdx.x;
  const float* in;
  ushortT* out;
  int blk;
  if (b < 4096) {
    in = x; out = ox; blk = b;
  } else if (b < 8192) {
    in = y; out = oy; blk = b - 4096;
  } else {
    int z = (b - 8192) >> 9;
    blk = (b - 8192) & 511;
    in = (z == 0) ? w0 : (z == 1) ? w1 : (z == 2) ? w2 : w3;
    out = (z == 0) ? o0 : (z == 1) ? o1 : (z == 2) ? o2 : o3;
  }
  int i = blk * 256 + threadIdx.x;
  const float4* p = (const float4*)in;
  float4 u = p[(size_t)i * 2];
  float4 v = p[(size_t)i * 2 + 1];
  ushort8 o;
  o[0] = f2bf(u.x); o[1] = f2bf(u.y); o[2] = f2bf(u.z); o[3] = f2bf(u.w);
  o[4] = f2bf(v.x); o[5] = f2bf(v.y); o[6] = f2bf(v.z); o[7] = f2bf(v.w);
  *(ushort8*)(out + (size_t)i * 8) = o;
}

// ---------------- GEMM, 8-phase 256x128 tile (m201-style template) ---------
// BM=256 BN=128 BK=64 (2 K-halves of 32), 512 thr = 8 waves (2M x 4N),
// per-wave output 128x32 (8 M-frags x 2 N-frags). LDS 96KB: lA 2x32KB,
// lB 2x16KB, 64B rows, slot^=(row&3) XOR swizzle (both sides, rule #21).
// Per K-tile, 4 phases: {ds_read quadrant | issue khalf stage -> barrier ->
// 8 MFMA (setprio) -> barrier}. Staging 1 tile ahead at khalf granularity;
// counted vmcnt(3) at phase-2/4 ends (wait-then-barrier = block-safe),
// sched_barrier(0) pinned only at the two validity barriers.
// Grid: 256 blocks/mode (32 M x 8 N); n-column == XCD -> W panel L2-resident.
// mode 0: Q=(x@Wq^T+bq)*c1  1: K=y@Wk^T+bk  2: V->[B,H,HD,S]  3: H=ctx@Wd^T+bd+x
__global__ __launch_bounds__(512, 2) void k_gemm(
    const ushortT* __restrict__ xbf, const ushortT* __restrict__ ybf,
    const ushortT* __restrict__ wq, const ushortT* __restrict__ wk,
    const ushortT* __restrict__ wv, const ushortT* __restrict__ wd,
    const float* __restrict__ bq, const float* __restrict__ bk,
    const float* __restrict__ bv, const float* __restrict__ bd,
    const ushortT* __restrict__ ctx, const float* __restrict__ xres,
    ushortT* __restrict__ Qo, ushortT* __restrict__ Ko,
    ushortT* __restrict__ Vt, float* __restrict__ Ho, int mode_base) {
  __shared__ char lA[2 * 32768];  // [buf][khalf 16KB][256 rows][64B]
  __shared__ char lB[2 * 16384];  // [buf][khalf 8KB][128 rows][64B]
  const int t = threadIdx.x;
  const int lane = t & 63;
  const int w = t >> 6;               // 0..7
  const int wm = w >> 2, wn = w & 3;  // 2 x 4 wave grid
  const int mode = mode_base + blockIdx.z;
  const int bid = blockIdx.x;
  const int m0 = (bid >> 3) * 256;
  const int n0 = (bid & 7) * 128;     // n-column == XCD (round-robin dispatch)

  const ushortT* A = (mode == 1) ? ybf : (mode == 3 ? ctx : xbf);
  const ushortT* W = (mode == 0) ? wq : (mode == 1 ? wk : (mode == 2 ? wv : wd));
  const float* bias = (mode == 0) ? bq : (mode == 1 ? bk : (mode == 2 ? bv : bd));

  f32x4 z = {0.f, 0.f, 0.f, 0.f};
  f32x4 acc[8][2];
#pragma unroll
  for (int i = 0; i < 8; ++i) {
    acc[i][0] = z;
    acc[i][1] = z;
  }

  // ---- staging precompute: thread t covers row ar_s=t>>2 (+128c for A),
  // 16B-quarter aq=t&3; source col pre-swizzled: q_log = aq ^ (ar_s&3).
  const int ar_s = t >> 2;
  const int aq = t & 3;
  const int tb = t * 16;  // LDS byte offset within a khalf block
  const ushortT* abase =
      A + (size_t)(m0 + ar_s) * 1024 + ((aq ^ (ar_s & 3)) * 8);
  const ushortT* bbase =
      W + (size_t)(n0 + ar_s) * 1024 + ((aq ^ (ar_s & 3)) * 8);

#define STG_A(buf, tt, h, c)                                          \
  load_lds16(abase + (size_t)(c) * 131072 + (tt) * 64 + (h) * 32,     \
             lA + (buf) * 32768 + (h) * 16384 + (c) * 8192 + tb)
#define STG_B(buf, tt, h)                                             \
  load_lds16(bbase + (tt) * 64 + (h) * 32,                            \
             lB + (buf) * 16384 + (h) * 8192 + tb)

  // ---- fragment-read precompute: row&3 == lane&3 for all frags
  const int aswz = ((lane >> 4) ^ (lane & 3)) << 4;
  const int arb = (wm * 128 + (lane & 15)) * 64 + aswz;  // + mi*1024 + h*16384
  const int brb = (wn * 32 + (lane & 15)) * 64 + aswz;   // + ni*1024 + h*8192

  // ---- prologue: stage tile 0 (kh0's 3 loads first), wait kh0, barrier
  STG_A(0, 0, 0, 0); STG_A(0, 0, 0, 1); STG_B(0, 0, 0);
  STG_A(0, 0, 1, 0); STG_A(0, 0, 1, 1); STG_B(0, 0, 1);
  asm volatile("s_waitcnt vmcnt(3)" ::: "memory");
  __builtin_amdgcn_s_barrier();
  __builtin_amdgcn_sched_barrier(0);

  for (int tt = 0; tt < 16; ++tt) {
    const int cur = tt & 1, nxt = cur ^ 1;
    const bool pf = (tt < 15);
    const char* lAc = lA + cur * 32768;
    const char* lBc = lB + cur * 16384;
    bf16x8 b0[2], b1[2], af[4];

    // ======== P1: kh0, mi 0-3 ========
#pragma unroll
    for (int ni = 0; ni < 2; ++ni)
      b0[ni] = *(const bf16x8*)(lBc + brb + ni * 1024);
#pragma unroll
    for (int mi = 0; mi < 4; ++mi)
      af[mi] = *(const bf16x8*)(lAc + arb + mi * 1024);
    if (pf) { STG_A(nxt, tt + 1, 0, 0); STG_A(nxt, tt + 1, 0, 1); }
    __builtin_amdgcn_s_barrier();
    __builtin_amdgcn_s_setprio(1);
#pragma unroll
    for (int mi = 0; mi < 4; ++mi) {
      acc[mi][0] = mfma16(af[mi], b0[0], acc[mi][0]);
      acc[mi][1] = mfma16(af[mi], b0[1], acc[mi][1]);
    }
    __builtin_amdgcn_s_setprio(0);
    __builtin_amdgcn_s_barrier();

    // ======== P2: kh0, mi 4-7 ========
#pragma unroll
    for (int mi = 0; mi < 4; ++mi)
      af[mi] = *(const bf16x8*)(lAc + arb + (4 + mi) * 1024);
    if (pf) STG_B(nxt, tt + 1, 0);
    __builtin_amdgcn_s_barrier();
    __builtin_amdgcn_s_setprio(1);
#pragma unroll
    for (int mi = 0; mi < 4; ++mi) {
      acc[4 + mi][0] = mfma16(af[mi], b0[0], acc[4 + mi][0]);
      acc[4 + mi][1] = mfma16(af[mi], b0[1], acc[4 + mi][1]);
    }
    __builtin_amdgcn_s_setprio(0);
    if (pf)
      asm volatile("s_waitcnt vmcnt(3)" ::: "memory");  // own-tile kh1 landed
    else
      asm volatile("s_waitcnt vmcnt(0)" ::: "memory");
    __builtin_amdgcn_s_barrier();
    __builtin_amdgcn_sched_barrier(0);

    // ======== P3: kh1, mi 0-3 ========
#pragma unroll
    for (int ni = 0; ni < 2; ++ni)
      b1[ni] = *(const bf16x8*)(lBc + 8192 + brb + ni * 1024);
#pragma unroll
    for (int mi = 0; mi < 4; ++mi)
      af[mi] = *(const bf16x8*)(lAc + 16384 + arb + mi * 1024);
    if (pf) { STG_A(nxt, tt + 1, 1, 0); STG_A(nxt, tt + 1, 1, 1); }
    __builtin_amdgcn_s_barrier();
    __builtin_amdgcn_s_setprio(1);
#pragma unroll
    for (int mi = 0; mi < 4; ++mi) {
      acc[mi][0] = mfma16(af[mi], b1[0], acc[mi][0]);
      acc[mi][1] = mfma16(af[mi], b1[1], acc[mi][1]);
    }
    __builtin_amdgcn_s_setprio(0);
    __builtin_amdgcn_s_barrier();

    // ======== P4: kh1, mi 4-7 ========
#pragma unroll
    for (int mi = 0; mi < 4; ++mi)
      af[mi] = *(const bf16x8*)(lAc + 16384 + arb + (4 + mi) * 1024);
    if (pf) STG_B(nxt, tt + 1, 1);
    __builtin_amdgcn_s_barrier();
    __builtin_amdgcn_s_setprio(1);
#pragma unroll
    for (int mi = 0; mi < 4; ++mi) {
      acc[4 + mi][0] = mfma16(af[mi], b1[0], acc[4 + mi][0]);
      acc[4 + mi][1] = mfma16(af[mi], b1[1], acc[4 + mi][1]);
    }
    __builtin_amdgcn_s_setprio(0);
    if (pf)
      asm volatile("s_waitcnt vmcnt(3)" ::: "memory");  // next-tile kh0 landed
    else
      asm volatile("s_waitcnt vmcnt(0)" ::: "memory");
    __builtin_amdgcn_s_barrier();
    __builtin_amdgcn_sched_barrier(0);
  }
#undef STG_A
#undef STG_B

  // ---- epilogue ----
  const int cmb = wm * 128 + (lane >> 4) * 4;  // + mi*16 + r
  const int cnb = wn * 32 + (lane & 15);       // + ni*16
  if (mode == 3) {
#pragma unroll
    for (int mi = 0; mi < 8; ++mi)
#pragma unroll
      for (int ni = 0; ni < 2; ++ni) {
        int n = n0 + cnb + ni * 16;
        float bn = bias[n];
#pragma unroll
        for (int r = 0; r < 4; ++r) {
          int m = m0 + cmb + mi * 16 + r;
          Ho[(size_t)m * 1024 + n] =
              acc[mi][ni][r] + bn + xres[(size_t)m * 1024 + n];
        }
      }
  } else if (mode == 2) {
#pragma unroll
    for (int mi = 0; mi < 8; ++mi)
#pragma unroll
      for (int ni = 0; ni < 2; ++ni) {
        int n = n0 + cnb + ni * 16;
        int hh = n >> 6, hd = n & 63;
        float bn = bias[n];
        int m_ = m0 + cmb + mi * 16;
        int b = m_ >> 11, s = m_ & 2047;
        ushort4v pk;
#pragma unroll
        for (int r = 0; r < 4; ++r) pk[r] = f2bf(acc[mi][ni][r] + bn);
        *(ushort4v*)&Vt[(((size_t)(b * 16 + hh) * 64 + hd) << 11) + s] = pk;
      }
  } else {
    ushortT* O = (mode == 0) ? Qo : Ko;
    // mode 0: fold softmax temperature (1/8)*log2(e) into Q.
    const float qs = (mode == 0) ? 0.18033688011112042f : 1.0f;
#pragma unroll
    for (int mi = 0; mi < 8; ++mi)
#pragma unroll
      for (int ni = 0; ni < 2; ++ni) {
        int n = n0 + cnb + ni * 16;
        int hh = n >> 6, hd = n & 63;
        float bn = bias[n];
#pragma unroll
        for (int r = 0; r < 4; ++r) {
          int m = m0 + cmb + mi * 16 + r;
          int b = m >> 11, s = m & 2047;
          O[(((size_t)(b * 16 + hh) * 2048 + s) << 6) + hd] =
              f2bf((acc[mi][ni][r] + bn) * qs);
        }
      }
  }
}

// ---------------- Flash attention, 4-wave swapped-QK^T 32x32 ----------------
// grid: 1024 blocks (16 qtiles x 64 bh), XCD-swizzled; block 256 = 4 waves.
// Each wave owns 32 q-rows; KV tile = 64 keys, double-buffered in LDS.
// Q prescaled by (1/8)*log2(e) in k_gemm -> p = exp2(sc) raw.
// Row-sums via MFMA with ones-B: accL[r] = sum_k P[k][q=qm(r,hi)].
__global__ __launch_bounds__(256, 4) void k_attn(const ushortT* __restrict__ Q,
                                                 const ushortT* __restrict__ K,
                                                 const ushortT* __restrict__ Vt,
                                                 ushortT* __restrict__ ctx) {
  __shared__ ushortT lK[2][4096];  // [buf][64 keys][64 d], 128B rows, XOR-swz
  __shared__ ushortT lV[2][4096];  // [buf][64 d][64 keys], 128B rows, XOR-swz
  const int t = threadIdx.x, lane = t & 63, w = t >> 6;
  const int hi = lane >> 5, l31 = lane & 31;
  const int i0 = blockIdx.x;
  const int xcd = i0 & 7, j0 = i0 >> 3;              // round-robin XCD map
  const int bh = xcd * 8 + (j0 >> 4);                // 8 bh per XCD -> L2-fit
  const int qt = j0 & 15;
  const int q0 = qt * 128 + w * 32;

  const ushortT* Qb = Q + ((size_t)bh * 2048 + q0) * 64;
  const ushortT* Kb = K + (size_t)bh * 2048 * 64;
  const ushortT* Vb = Vt + (size_t)bh * 64 * 2048;

  // Q fragments (B-operand): Q[q=l31, d = dc*16 + hi*8 + j]
  bf16x8 qf[4];
#pragma unroll
  for (int dc = 0; dc < 4; ++dc)
    qf[dc] = *(const bf16x8*)(Qb + l31 * 64 + dc * 16 + hi * 8);

  // ones B-operand for row-sum MFMA
  union { unsigned short us[8]; bf16x8 v; } ones_u;
#pragma unroll
  for (int i = 0; i < 8; ++i) ones_u.us[i] = 0x3F80;

  f32x16 accO0, accO1, accL;
#pragma unroll
  for (int i = 0; i < 16; ++i) { accO0[i] = 0.f; accO1[i] = 0.f; accL[i] = 0.f; }

  // staging: linear LDS dest, pre-swizzled global source (rule #21)
  const int srow = t >> 3;                 // 0..31
  const int scolb = ((t & 7) * 16) ^ ((srow & 7) << 4);
  const ushortT* ksrc = Kb + srow * 64 + (scolb >> 1);
  const ushortT* vsrc = Vb + (size_t)srow * 2048 + (scolb >> 1);
  const int swz = (lane & 7) << 4;
  const int hs = (hi * 16) ^ swz;
  const int krowb = l31 * 128;

#define STAGE(buf, kk)                                                        \
  do {                                                                        \
    load_lds16(ksrc + (size_t)(kk) * 64, (char*)&lK[buf][0] + w * 1024);      \
    load_lds16(ksrc + 2048 + (size_t)(kk) * 64,                               \
               (char*)&lK[buf][0] + 4096 + w * 1024);                         \
    load_lds16(vsrc + (kk), (char*)&lV[buf][0] + w * 1024);                   \
    load_lds16(vsrc + 65536 + (kk), (char*)&lV[buf][0] + 4096 + w * 1024);    \
  } while (0)

  STAGE(0, 0);
  __syncthreads();
  int cur = 0;
  for (int k0 = 0; k0 < 2048; k0 += 64) {
    if (k0 + 64 < 2048) STAGE(cur ^ 1, k0 + 64);
    const char* lKc = (const char*)&lK[cur][0];
    const char* lVc = (const char*)&lV[cur][0];
#pragma unroll
    for (int kb = 0; kb < 2; ++kb) {
      // ---- QK^T (swapped): sc[r] = S[krow(r,hi), q=l31]
      f32x16 sc;
#pragma unroll
      for (int i = 0; i < 16; ++i) sc[i] = 0.f;
      __builtin_amdgcn_s_setprio(1);
#pragma unroll
      for (int dc = 0; dc < 4; ++dc) {
        bf16x8 kf = *(const bf16x8*)(lKc + kb * 4096 + krowb + ((dc * 32) ^ hs));
        sc = mfma32(kf, qf[dc], sc);
      }
      __builtin_amdgcn_s_setprio(0);
      // ---- softmax numerator: p = exp2(sc) (raw v_exp_f32, no ocml fixup)
      float p[16];
#pragma unroll
      for (int r = 0; r < 16; ++r) p[r] = __builtin_amdgcn_exp2f(sc[r]);
      // ---- pack P -> bf16 words (cvt_pk); exchange halves (permlane32_swap)
      union { unsigned u[4]; bf16x8 v; } pa0, pa1;
#pragma unroll
      for (int i = 0; i < 4; ++i) {
        int base = (i >> 1) * 8 + (i & 1) * 2;  // 0,2,8,10
        unsigned a = cvtpk_bf16(p[base], p[base + 1]);        // keys 4hi+b..
        unsigned b = cvtpk_bf16(p[base + 4], p[base + 5]);    // keys 8+4hi+b..
        asm("v_permlane32_swap_b32 %0, %1" : "+v"(a), "+v"(b));
        if (i >> 1) { pa1.u[i & 1] = a; pa1.u[2 + (i & 1)] = b; }
        else        { pa0.u[i & 1] = a; pa0.u[2 + (i & 1)] = b; }
      }
      // ---- PV + row-sum: accO[nb] += P x V ; accL += P x ones
      __builtin_amdgcn_s_setprio(1);
#pragma unroll
      for (int nb = 0; nb < 2; ++nb) {
        const char* vrow = lVc + (nb * 32 + l31) * 128;
        bf16x8 vf0 = *(const bf16x8*)(vrow + ((kb * 64) ^ hs));
        bf16x8 vf1 = *(const bf16x8*)(vrow + ((kb * 64 + 32) ^ hs));
        f32x16& ao = nb ? accO1 : accO0;
        ao = mfma32(pa0.v, vf0, ao);
        ao = mfma32(pa1.v, vf1, ao);
      }
      accL = mfma32(pa0.v, ones_u.v, accL);
      accL = mfma32(pa1.v, ones_u.v, accL);
      __builtin_amdgcn_s_setprio(0);
    }
    __syncthreads();
    cur ^= 1;
  }
#undef STAGE

  // epilogue: O[q,d] = accO/accL -> ctx[B,S,D] bf16
  int b = bh >> 4, hh = bh & 15;
  ushortT* cb = ctx + ((size_t)(b * 2048 + q0)) * 1024 + hh * 64;
#pragma unroll
  for (int r = 0; r < 16; ++r) {
    int qm = (r & 3) + 8 * (r >> 2) + 4 * hi;
    float lr = 1.0f / accL[r];
    size_t rb = (size_t)qm * 1024;
    cb[rb + l31] = f2bf(accO0[r] * lr);
    cb[rb + 32 + l31] = f2bf(accO1[r] * lr);
  }
}

// ---------------- LayerNorm (one row per block) ----------------
__global__ __launch_bounds__(256) void k_ln(const float* __restrict__ Hi,
                                            const float* __restrict__ gamma,
                                            const float* __restrict__ beta,
                                            float* __restrict__ out) {
  const int row = blockIdx.x, t = threadIdx.x, lane = t & 63, w = t >> 6;
  const float4* hp = (const float4*)(Hi + (size_t)row * 1024);
  float4 v = hp[t];
  float s1 = v.x + v.y + v.z + v.w;
  float s2 = v.x * v.x + v.y * v.y + v.z * v.z + v.w * v.w;
#pragma unroll
  for (int off = 1; off < 64; off <<= 1) {
    s1 += __shfl_xor(s1, off);
    s2 += __shfl_xor(s2, off);
  }
  __shared__ float red[8];
  if (lane == 0) { red[w] = s1; red[4 + w] = s2; }
  __syncthreads();
  s1 = red[0] + red[1] + red[2] + red[3];
  s2 = red[4] + red[5] + red[6] + red[7];
  float u = s1 * (1.f / 1024.f);
  float var = s2 * (1.f / 1024.f) - u * u;
  float rstd = rsqrtf(var + 1e-12f);
  float4 g = ((const float4*)gamma)[t];
  float4 bb = ((const float4*)beta)[t];
  float4 oo;
  oo.x = (v.x - u) * rstd * g.x + bb.x;
  oo.y = (v.y - u) * rstd * g.y + bb.y;
  oo.z = (v.z - u) * rstd * g.z + bb.z;
  oo.w = (v.w - u) * rstd * g.w + bb.w;
  ((float4*)(out + (size_t)row * 1024))[t] = oo;
}

extern "C" void kernel_launch(void* const* d_in, const int* in_sizes, int n_in,
                              void* d_out, int out_size, void* d_ws,
                              size_t ws_size, hipStream_t stream) {
  const float* x = (const float*)d_in[0];
  const float* y = (const float*)d_in[1];
  const float* Wq = (const float*)d_in[2];
  const float* bq = (const float*)d_in[3];
  const float* Wk = (const float*)d_in[4];
  const float* bk = (const float*)d_in[5];
  const float* Wv = (const float*)d_in[6];
  const float* bv = (const float*)d_in[7];
  const float* Wd = (const float*)d_in[8];
  const float* bd = (const float*)d_in[9];
  const float* gamma = (const float*)d_in[10];
  const float* beta = (const float*)d_in[11];

  char* ws = (char*)d_ws;
  ushortT* xbf = (ushortT*)(ws + 0);          // 16 MiB
  ushortT* ybf = (ushortT*)(ws + 16777216);   // 16 MiB
  ushortT* wqb = (ushortT*)(ws + 33554432);   // 2 MiB
  ushortT* wkb = (ushortT*)(ws + 35651584);
  ushortT* wvb = (ushortT*)(ws + 37748736);
  ushortT* wdb = (ushortT*)(ws + 39845888);
  ushortT* Qb = (ushortT*)(ws + 41943040);    // 16 MiB
  ushortT* Kb = (ushortT*)(ws + 58720256);    // 16 MiB
  ushortT* Vtb = (ushortT*)(ws + 75497472);   // 16 MiB
  ushortT* ctx = (ushortT*)(ws + 92274688);   // 16 MiB
  float* Hbuf = (float*)(ws + 0);  // 32 MiB, reuses xbf+ybf (dead by then)

  k_cvt_all<<<10240, 256, 0, stream>>>(x, y, Wq, Wk, Wv, Wd, xbf, ybf, wqb,
                                       wkb, wvb, wdb);

  k_gemm<<<dim3(256, 1, 3), 512, 0, stream>>>(xbf, ybf, wqb, wkb, wvb, wdb,
                                              bq, bk, bv, bd, ctx, x, Qb, Kb,
                                              Vtb, Hbuf, 0);
  k_attn<<<1024, 256, 0, stream>>>(Qb, Kb, Vtb, ctx);
  k_gemm<<<dim3(256, 1, 1), 512, 0, stream>>>(xbf, ybf, wqb, wkb, wvb, wdb,
                                              bq, bk, bv, bd, ctx, x, Qb, Kb,
                                              Vtb, Hbuf, 3);
  k_ln<<<8192, 256, 0, stream>>>(Hbuf, gamma, beta, (float*)d_out);
}

// Round 12
// 228.288 us; speedup vs baseline: 1.1154x; 1.1154x over previous
//
#include <hip/hip_runtime.h>
#include <hip/hip_bf16.h>
#include <stdint.h>

// Problem constants: B=4, S=2048, D=1024, H=16, HD=64, M = B*S = 8192.

typedef unsigned short ushortT;
typedef __attribute__((ext_vector_type(8))) __bf16 bf16x8;
typedef __attribute__((ext_vector_type(4))) float f32x4;
typedef __attribute__((ext_vector_type(16))) float f32x16;
typedef __attribute__((ext_vector_type(8))) unsigned short ushort8;
typedef __attribute__((ext_vector_type(4))) unsigned short ushort4v;

__device__ __forceinline__ unsigned short f2bf(float f) {
  union { float f; unsigned u; } x; x.f = f;
  unsigned r = (x.u + 0x7FFFu + ((x.u >> 16) & 1u)) >> 16;  // RNE
  return (unsigned short)r;
}

// packed f32x2 -> bf16x2 (RNE), dst[15:0]=lo, dst[31:16]=hi
__device__ __forceinline__ unsigned cvtpk_bf16(float lo, float hi) {
  unsigned r;
  asm("v_cvt_pk_bf16_f32 %0, %1, %2" : "=v"(r) : "v"(lo), "v"(hi));
  return r;
}

__device__ __forceinline__ void load_lds16(const void* g, void* l) {
  __builtin_amdgcn_global_load_lds(
      (const __attribute__((address_space(1))) void*)g,
      (__attribute__((address_space(3))) void*)l, 16, 0, 0);
}

__device__ __forceinline__ f32x4 mfma16(bf16x8 a, bf16x8 b, f32x4 c) {
  return __builtin_amdgcn_mfma_f32_16x16x32_bf16(a, b, c, 0, 0, 0);
}
__device__ __forceinline__ f32x16 mfma32(bf16x8 a, bf16x8 b, f32x16 c) {
  return __builtin_amdgcn_mfma_f32_32x32x16_bf16(a, b, c, 0, 0, 0);
}

// ---------------- f32 -> bf16 convert, all 6 tensors in one launch ---------
__global__ __launch_bounds__(256) void k_cvt_all(
    const float* __restrict__ x, const float* __restrict__ y,
    const float* __restrict__ w0, const float* __restrict__ w1,
    const float* __restrict__ w2, const float* __restrict__ w3,
    ushortT* __restrict__ ox, ushortT* __restrict__ oy,
    ushortT* __restrict__ o0, ushortT* __restrict__ o1,
    ushortT* __restrict__ o2, ushortT* __restrict__ o3) {
  int b = blockIdx.x;
  const float* in;
  ushortT* out;
  int blk;
  if (b < 4096) {
    in = x; out = ox; blk = b;
  } else if (b < 8192) {
    in = y; out = oy; blk = b - 4096;
  } else {
    int z = (b - 8192) >> 9;
    blk = (b - 8192) & 511;
    in = (z == 0) ? w0 : (z == 1) ? w1 : (z == 2) ? w2 : w3;
    out = (z == 0) ? o0 : (z == 1) ? o1 : (z == 2) ? o2 : o3;
  }
  int i = blk * 256 + threadIdx.x;
  const float4* p = (const float4*)in;
  float4 u = p[(size_t)i * 2];
  float4 v = p[(size_t)i * 2 + 1];
  ushort8 o;
  o[0] = f2bf(u.x); o[1] = f2bf(u.y); o[2] = f2bf(u.z); o[3] = f2bf(u.w);
  o[4] = f2bf(v.x); o[5] = f2bf(v.y); o[6] = f2bf(v.z); o[7] = f2bf(v.w);
  *(ushort8*)(out + (size_t)i * 8) = o;
}

// ---------------- GEMM, 8-phase 256x128 tile (m201-style template) ---------
// BM=256 BN=128 BK=64 (2 K-halves of 32), 512 thr = 8 waves (2M x 4N),
// per-wave output 128x32. LDS 96KB (1 block/CU): lA 2x32KB, lB 2x16KB,
// 64B rows, slot^=(row&3) XOR swizzle (both sides, rule #21).
// XCD mapping (r11 post-mortem fix): HW dispatches block b to XCD b&7, so
// XCD must own an M-BAND, not an N-column: xcd=bid&7 -> m-tiles [4xcd,4xcd+4)
// x all 8 n. Per-XCD working set = A band 2MB + W 2MB = 4MB = one L2.
// (r11's n0=(bid&7)*128 made every XCD fetch the whole 16MB A -> 200MB FETCH.)
// mode 0: Q=(x@Wq^T+bq)*c1  1: K=y@Wk^T+bk  2: V->[B,H,HD,S]  3: H=ctx@Wd^T+bd+x
__global__ __launch_bounds__(512, 2) void k_gemm(
    const ushortT* __restrict__ xbf, const ushortT* __restrict__ ybf,
    const ushortT* __restrict__ wq, const ushortT* __restrict__ wk,
    const ushortT* __restrict__ wv, const ushortT* __restrict__ wd,
    const float* __restrict__ bq, const float* __restrict__ bk,
    const float* __restrict__ bv, const float* __restrict__ bd,
    const ushortT* __restrict__ ctx, const float* __restrict__ xres,
    ushortT* __restrict__ Qo, ushortT* __restrict__ Ko,
    ushortT* __restrict__ Vt, float* __restrict__ Ho, int mode_base) {
  __shared__ char lA[2 * 32768];  // [buf][khalf 16KB][256 rows][64B]
  __shared__ char lB[2 * 16384];  // [buf][khalf 8KB][128 rows][64B]
  const int t = threadIdx.x;
  const int lane = t & 63;
  const int w = t >> 6;               // 0..7
  const int wm = w >> 2, wn = w & 3;  // 2 x 4 wave grid
  const int mode = mode_base + blockIdx.z;
  const int bid = blockIdx.x;
  const int xcd = bid & 7, j = bid >> 3;
  const int m0 = (xcd * 4 + (j & 3)) * 256;  // XCD owns a 1024-row M band
  const int n0 = (j >> 2) * 128;

  const ushortT* A = (mode == 1) ? ybf : (mode == 3 ? ctx : xbf);
  const ushortT* W = (mode == 0) ? wq : (mode == 1 ? wk : (mode == 2 ? wv : wd));
  const float* bias = (mode == 0) ? bq : (mode == 1 ? bk : (mode == 2 ? bv : bd));

  f32x4 z = {0.f, 0.f, 0.f, 0.f};
  f32x4 acc[8][2];
#pragma unroll
  for (int i = 0; i < 8; ++i) {
    acc[i][0] = z;
    acc[i][1] = z;
  }

  // ---- staging precompute: thread t covers row ar_s=t>>2 (+128c for A),
  // 16B-quarter aq=t&3; source col pre-swizzled: q_log = aq ^ (ar_s&3).
  const int ar_s = t >> 2;
  const int aq = t & 3;
  const int tb = t * 16;  // LDS byte offset within a khalf block
  const ushortT* abase =
      A + (size_t)(m0 + ar_s) * 1024 + ((aq ^ (ar_s & 3)) * 8);
  const ushortT* bbase =
      W + (size_t)(n0 + ar_s) * 1024 + ((aq ^ (ar_s & 3)) * 8);

#define STG_A(buf, tt, h, c)                                          \
  load_lds16(abase + (size_t)(c) * 131072 + (tt) * 64 + (h) * 32,     \
             lA + (buf) * 32768 + (h) * 16384 + (c) * 8192 + tb)
#define STG_B(buf, tt, h)                                             \
  load_lds16(bbase + (tt) * 64 + (h) * 32,                            \
             lB + (buf) * 16384 + (h) * 8192 + tb)

  // ---- fragment-read precompute: row&3 == lane&3 for all frags
  const int aswz = ((lane >> 4) ^ (lane & 3)) << 4;
  const int arb = (wm * 128 + (lane & 15)) * 64 + aswz;  // + mi*1024 + h*16384
  const int brb = (wn * 32 + (lane & 15)) * 64 + aswz;   // + ni*1024 + h*8192

  // ---- prologue: stage tile 0 (kh0's 3 loads first), wait kh0, barrier
  STG_A(0, 0, 0, 0); STG_A(0, 0, 0, 1); STG_B(0, 0, 0);
  STG_A(0, 0, 1, 0); STG_A(0, 0, 1, 1); STG_B(0, 0, 1);
  asm volatile("s_waitcnt vmcnt(3)" ::: "memory");
  __builtin_amdgcn_s_barrier();
  __builtin_amdgcn_sched_barrier(0);

  for (int tt = 0; tt < 16; ++tt) {
    const int cur = tt & 1, nxt = cur ^ 1;
    const bool pf = (tt < 15);
    const char* lAc = lA + cur * 32768;
    const char* lBc = lB + cur * 16384;
    bf16x8 b0[2], b1[2], af[4];

    // ======== P1: kh0, mi 0-3 ========
#pragma unroll
    for (int ni = 0; ni < 2; ++ni)
      b0[ni] = *(const bf16x8*)(lBc + brb + ni * 1024);
#pragma unroll
    for (int mi = 0; mi < 4; ++mi)
      af[mi] = *(const bf16x8*)(lAc + arb + mi * 1024);
    if (pf) { STG_A(nxt, tt + 1, 0, 0); STG_A(nxt, tt + 1, 0, 1); }
    __builtin_amdgcn_s_barrier();
    __builtin_amdgcn_s_setprio(1);
#pragma unroll
    for (int mi = 0; mi < 4; ++mi) {
      acc[mi][0] = mfma16(af[mi], b0[0], acc[mi][0]);
      acc[mi][1] = mfma16(af[mi], b0[1], acc[mi][1]);
    }
    __builtin_amdgcn_s_setprio(0);
    __builtin_amdgcn_s_barrier();

    // ======== P2: kh0, mi 4-7 ========
#pragma unroll
    for (int mi = 0; mi < 4; ++mi)
      af[mi] = *(const bf16x8*)(lAc + arb + (4 + mi) * 1024);
    if (pf) STG_B(nxt, tt + 1, 0);
    __builtin_amdgcn_s_barrier();
    __builtin_amdgcn_s_setprio(1);
#pragma unroll
    for (int mi = 0; mi < 4; ++mi) {
      acc[4 + mi][0] = mfma16(af[mi], b0[0], acc[4 + mi][0]);
      acc[4 + mi][1] = mfma16(af[mi], b0[1], acc[4 + mi][1]);
    }
    __builtin_amdgcn_s_setprio(0);
    if (pf)
      asm volatile("s_waitcnt vmcnt(3)" ::: "memory");  // own-tile kh1 landed
    else
      asm volatile("s_waitcnt vmcnt(0)" ::: "memory");
    __builtin_amdgcn_s_barrier();
    __builtin_amdgcn_sched_barrier(0);

    // ======== P3: kh1, mi 0-3 ========
#pragma unroll
    for (int ni = 0; ni < 2; ++ni)
      b1[ni] = *(const bf16x8*)(lBc + 8192 + brb + ni * 1024);
#pragma unroll
    for (int mi = 0; mi < 4; ++mi)
      af[mi] = *(const bf16x8*)(lAc + 16384 + arb + mi * 1024);
    if (pf) { STG_A(nxt, tt + 1, 1, 0); STG_A(nxt, tt + 1, 1, 1); }
    __builtin_amdgcn_s_barrier();
    __builtin_amdgcn_s_setprio(1);
#pragma unroll
    for (int mi = 0; mi < 4; ++mi) {
      acc[mi][0] = mfma16(af[mi], b1[0], acc[mi][0]);
      acc[mi][1] = mfma16(af[mi], b1[1], acc[mi][1]);
    }
    __builtin_amdgcn_s_setprio(0);
    __builtin_amdgcn_s_barrier();

    // ======== P4: kh1, mi 4-7 ========
#pragma unroll
    for (int mi = 0; mi < 4; ++mi)
      af[mi] = *(const bf16x8*)(lAc + 16384 + arb + (4 + mi) * 1024);
    if (pf) STG_B(nxt, tt + 1, 1);
    __builtin_amdgcn_s_barrier();
    __builtin_amdgcn_s_setprio(1);
#pragma unroll
    for (int mi = 0; mi < 4; ++mi) {
      acc[4 + mi][0] = mfma16(af[mi], b1[0], acc[4 + mi][0]);
      acc[4 + mi][1] = mfma16(af[mi], b1[1], acc[4 + mi][1]);
    }
    __builtin_amdgcn_s_setprio(0);
    if (pf)
      asm volatile("s_waitcnt vmcnt(3)" ::: "memory");  // next-tile kh0 landed
    else
      asm volatile("s_waitcnt vmcnt(0)" ::: "memory");
    __builtin_amdgcn_s_barrier();
    __builtin_amdgcn_sched_barrier(0);
  }
#undef STG_A
#undef STG_B

  // ---- epilogue ----
  const int cmb = wm * 128 + (lane >> 4) * 4;  // + mi*16 + r
  const int cnb = wn * 32 + (lane & 15);       // + ni*16
  if (mode == 3) {
#pragma unroll
    for (int mi = 0; mi < 8; ++mi)
#pragma unroll
      for (int ni = 0; ni < 2; ++ni) {
        int n = n0 + cnb + ni * 16;
        float bn = bias[n];
#pragma unroll
        for (int r = 0; r < 4; ++r) {
          int m = m0 + cmb + mi * 16 + r;
          Ho[(size_t)m * 1024 + n] =
              acc[mi][ni][r] + bn + xres[(size_t)m * 1024 + n];
        }
      }
  } else if (mode == 2) {
#pragma unroll
    for (int mi = 0; mi < 8; ++mi)
#pragma unroll
      for (int ni = 0; ni < 2; ++ni) {
        int n = n0 + cnb + ni * 16;
        int hh = n >> 6, hd = n & 63;
        float bn = bias[n];
        int m_ = m0 + cmb + mi * 16;
        int b = m_ >> 11, s = m_ & 2047;
        ushort4v pk;
#pragma unroll
        for (int r = 0; r < 4; ++r) pk[r] = f2bf(acc[mi][ni][r] + bn);
        *(ushort4v*)&Vt[(((size_t)(b * 16 + hh) * 64 + hd) << 11) + s] = pk;
      }
  } else {
    ushortT* O = (mode == 0) ? Qo : Ko;
    // mode 0: fold softmax temperature (1/8)*log2(e) into Q.
    const float qs = (mode == 0) ? 0.18033688011112042f : 1.0f;
#pragma unroll
    for (int mi = 0; mi < 8; ++mi)
#pragma unroll
      for (int ni = 0; ni < 2; ++ni) {
        int n = n0 + cnb + ni * 16;
        int hh = n >> 6, hd = n & 63;
        float bn = bias[n];
#pragma unroll
        for (int r = 0; r < 4; ++r) {
          int m = m0 + cmb + mi * 16 + r;
          int b = m >> 11, s = m & 2047;
          O[(((size_t)(b * 16 + hh) * 2048 + s) << 6) + hd] =
              f2bf((acc[mi][ni][r] + bn) * qs);
        }
      }
  }
}

// ---------------- Flash attention, 4-wave swapped-QK^T 32x32 ----------------
// grid: 1024 blocks (16 qtiles x 64 bh), XCD-swizzled; block 256 = 4 waves.
// Each wave owns 32 q-rows; KV tile = 64 keys, double-buffered in LDS.
// Q prescaled by (1/8)*log2(e) in k_gemm -> p = exp2(sc) raw.
// Row-sums via MFMA with ones-B: accL[r] = sum_k P[k][q=qm(r,hi)].
__global__ __launch_bounds__(256, 4) void k_attn(const ushortT* __restrict__ Q,
                                                 const ushortT* __restrict__ K,
                                                 const ushortT* __restrict__ Vt,
                                                 ushortT* __restrict__ ctx) {
  __shared__ ushortT lK[2][4096];  // [buf][64 keys][64 d], 128B rows, XOR-swz
  __shared__ ushortT lV[2][4096];  // [buf][64 d][64 keys], 128B rows, XOR-swz
  const int t = threadIdx.x, lane = t & 63, w = t >> 6;
  const int hi = lane >> 5, l31 = lane & 31;
  const int i0 = blockIdx.x;
  const int xcd = i0 & 7, j0 = i0 >> 3;              // round-robin XCD map
  const int bh = xcd * 8 + (j0 >> 4);                // 8 bh per XCD -> L2-fit
  const int qt = j0 & 15;
  const int q0 = qt * 128 + w * 32;

  const ushortT* Qb = Q + ((size_t)bh * 2048 + q0) * 64;
  const ushortT* Kb = K + (size_t)bh * 2048 * 64;
  const ushortT* Vb = Vt + (size_t)bh * 64 * 2048;

  // Q fragments (B-operand): Q[q=l31, d = dc*16 + hi*8 + j]
  bf16x8 qf[4];
#pragma unroll
  for (int dc = 0; dc < 4; ++dc)
    qf[dc] = *(const bf16x8*)(Qb + l31 * 64 + dc * 16 + hi * 8);

  // ones B-operand for row-sum MFMA
  union { unsigned short us[8]; bf16x8 v; } ones_u;
#pragma unroll
  for (int i = 0; i < 8; ++i) ones_u.us[i] = 0x3F80;

  f32x16 accO0, accO1, accL;
#pragma unroll
  for (int i = 0; i < 16; ++i) { accO0[i] = 0.f; accO1[i] = 0.f; accL[i] = 0.f; }

  // staging: linear LDS dest, pre-swizzled global source (rule #21)
  const int srow = t >> 3;                 // 0..31
  const int scolb = ((t & 7) * 16) ^ ((srow & 7) << 4);
  const ushortT* ksrc = Kb + srow * 64 + (scolb >> 1);
  const ushortT* vsrc = Vb + (size_t)srow * 2048 + (scolb >> 1);
  const int swz = (lane & 7) << 4;
  const int hs = (hi * 16) ^ swz;
  const int krowb = l31 * 128;

#define STAGE(buf, kk)                                                        \
  do {                                                                        \
    load_lds16(ksrc + (size_t)(kk) * 64, (char*)&lK[buf][0] + w * 1024);      \
    load_lds16(ksrc + 2048 + (size_t)(kk) * 64,                               \
               (char*)&lK[buf][0] + 4096 + w * 1024);                         \
    load_lds16(vsrc + (kk), (char*)&lV[buf][0] + w * 1024);                   \
    load_lds16(vsrc + 65536 + (kk), (char*)&lV[buf][0] + 4096 + w * 1024);    \
  } while (0)

  STAGE(0, 0);
  __syncthreads();
  int cur = 0;
  for (int k0 = 0; k0 < 2048; k0 += 64) {
    if (k0 + 64 < 2048) STAGE(cur ^ 1, k0 + 64);
    const char* lKc = (const char*)&lK[cur][0];
    const char* lVc = (const char*)&lV[cur][0];
#pragma unroll
    for (int kb = 0; kb < 2; ++kb) {
      // ---- QK^T (swapped): sc[r] = S[krow(r,hi), q=l31]
      f32x16 sc;
#pragma unroll
      for (int i = 0; i < 16; ++i) sc[i] = 0.f;
      __builtin_amdgcn_s_setprio(1);
#pragma unroll
      for (int dc = 0; dc < 4; ++dc) {
        bf16x8 kf = *(const bf16x8*)(lKc + kb * 4096 + krowb + ((dc * 32) ^ hs));
        sc = mfma32(kf, qf[dc], sc);
      }
      __builtin_amdgcn_s_setprio(0);
      // ---- softmax numerator: p = exp2(sc) (raw v_exp_f32, no ocml fixup)
      float p[16];
#pragma unroll
      for (int r = 0; r < 16; ++r) p[r] = __builtin_amdgcn_exp2f(sc[r]);
      // ---- pack P -> bf16 words (cvt_pk); exchange halves (permlane32_swap)
      union { unsigned u[4]; bf16x8 v; } pa0, pa1;
#pragma unroll
      for (int i = 0; i < 4; ++i) {
        int base = (i >> 1) * 8 + (i & 1) * 2;  // 0,2,8,10
        unsigned a = cvtpk_bf16(p[base], p[base + 1]);        // keys 4hi+b..
        unsigned b = cvtpk_bf16(p[base + 4], p[base + 5]);    // keys 8+4hi+b..
        asm("v_permlane32_swap_b32 %0, %1" : "+v"(a), "+v"(b));
        if (i >> 1) { pa1.u[i & 1] = a; pa1.u[2 + (i & 1)] = b; }
        else        { pa0.u[i & 1] = a; pa0.u[2 + (i & 1)] = b; }
      }
      // ---- PV + row-sum: accO[nb] += P x V ; accL += P x ones
      __builtin_amdgcn_s_setprio(1);
#pragma unroll
      for (int nb = 0; nb < 2; ++nb) {
        const char* vrow = lVc + (nb * 32 + l31) * 128;
        bf16x8 vf0 = *(const bf16x8*)(vrow + ((kb * 64) ^ hs));
        bf16x8 vf1 = *(const bf16x8*)(vrow + ((kb * 64 + 32) ^ hs));
        f32x16& ao = nb ? accO1 : accO0;
        ao = mfma32(pa0.v, vf0, ao);
        ao = mfma32(pa1.v, vf1, ao);
      }
      accL = mfma32(pa0.v, ones_u.v, accL);
      accL = mfma32(pa1.v, ones_u.v, accL);
      __builtin_amdgcn_s_setprio(0);
    }
    __syncthreads();
    cur ^= 1;
  }
#undef STAGE

  // epilogue: O[q,d] = accO/accL -> ctx[B,S,D] bf16
  int b = bh >> 4, hh = bh & 15;
  ushortT* cb = ctx + ((size_t)(b * 2048 + q0)) * 1024 + hh * 64;
#pragma unroll
  for (int r = 0; r < 16; ++r) {
    int qm = (r & 3) + 8 * (r >> 2) + 4 * hi;
    float lr = 1.0f / accL[r];
    size_t rb = (size_t)qm * 1024;
    cb[rb + l31] = f2bf(accO0[r] * lr);
    cb[rb + 32 + l31] = f2bf(accO1[r] * lr);
  }
}

// ---------------- LayerNorm (one row per block) ----------------
__global__ __launch_bounds__(256) void k_ln(const float* __restrict__ Hi,
                                            const float* __restrict__ gamma,
                                            const float* __restrict__ beta,
                                            float* __restrict__ out) {
  const int row = blockIdx.x, t = threadIdx.x, lane = t & 63, w = t >> 6;
  const float4* hp = (const float4*)(Hi + (size_t)row * 1024);
  float4 v = hp[t];
  float s1 = v.x + v.y + v.z + v.w;
  float s2 = v.x * v.x + v.y * v.y + v.z * v.z + v.w * v.w;
#pragma unroll
  for (int off = 1; off < 64; off <<= 1) {
    s1 += __shfl_xor(s1, off);
    s2 += __shfl_xor(s2, off);
  }
  __shared__ float red[8];
  if (lane == 0) { red[w] = s1; red[4 + w] = s2; }
  __syncthreads();
  s1 = red[0] + red[1] + red[2] + red[3];
  s2 = red[4] + red[5] + red[6] + red[7];
  float u = s1 * (1.f / 1024.f);
  float var = s2 * (1.f / 1024.f) - u * u;
  float rstd = rsqrtf(var + 1e-12f);
  float4 g = ((const float4*)gamma)[t];
  float4 bb = ((const float4*)beta)[t];
  float4 oo;
  oo.x = (v.x - u) * rstd * g.x + bb.x;
  oo.y = (v.y - u) * rstd * g.y + bb.y;
  oo.z = (v.z - u) * rstd * g.z + bb.z;
  oo.w = (v.w - u) * rstd * g.w + bb.w;
  ((float4*)(out + (size_t)row * 1024))[t] = oo;
}

extern "C" void kernel_launch(void* const* d_in, const int* in_sizes, int n_in,
                              void* d_out, int out_size, void* d_ws,
                              size_t ws_size, hipStream_t stream) {
  const float* x = (const float*)d_in[0];
  const float* y = (const float*)d_in[1];
  const float* Wq = (const float*)d_in[2];
  const float* bq = (const float*)d_in[3];
  const float* Wk = (const float*)d_in[4];
  const float* bk = (const float*)d_in[5];
  const float* Wv = (const float*)d_in[6];
  const float* bv = (const float*)d_in[7];
  const float* Wd = (const float*)d_in[8];
  const float* bd = (const float*)d_in[9];
  const float* gamma = (const float*)d_in[10];
  const float* beta = (const float*)d_in[11];

  char* ws = (char*)d_ws;
  ushortT* xbf = (ushortT*)(ws + 0);          // 16 MiB
  ushortT* ybf = (ushortT*)(ws + 16777216);   // 16 MiB
  ushortT* wqb = (ushortT*)(ws + 33554432);   // 2 MiB
  ushortT* wkb = (ushortT*)(ws + 35651584);
  ushortT* wvb = (ushortT*)(ws + 37748736);
  ushortT* wdb = (ushortT*)(ws + 39845888);
  ushortT* Qb = (ushortT*)(ws + 41943040);    // 16 MiB
  ushortT* Kb = (ushortT*)(ws + 58720256);    // 16 MiB
  ushortT* Vtb = (ushortT*)(ws + 75497472);   // 16 MiB
  ushortT* ctx = (ushortT*)(ws + 92274688);   // 16 MiB
  float* Hbuf = (float*)(ws + 0);  // 32 MiB, reuses xbf+ybf (dead by then)

  k_cvt_all<<<10240, 256, 0, stream>>>(x, y, Wq, Wk, Wv, Wd, xbf, ybf, wqb,
                                       wkb, wvb, wdb);

  k_gemm<<<dim3(256, 1, 3), 512, 0, stream>>>(xbf, ybf, wqb, wkb, wvb, wdb,
                                              bq, bk, bv, bd, ctx, x, Qb, Kb,
                                              Vtb, Hbuf, 0);
  k_attn<<<1024, 256, 0, stream>>>(Qb, Kb, Vtb, ctx);
  k_gemm<<<dim3(256, 1, 1), 512, 0, stream>>>(xbf, ybf, wqb, wkb, wvb, wdb,
                                              bq, bk, bv, bd, ctx, x, Qb, Kb,
                                              Vtb, Hbuf, 3);
  k_ln<<<8192, 256, 0, stream>>>(Hbuf, gamma, beta, (float*)d_out);
}

// Round 13
// 228.074 us; speedup vs baseline: 1.1164x; 1.0009x over previous
//
#include <hip/hip_runtime.h>
#include <hip/hip_bf16.h>
#include <stdint.h>

// Problem constants: B=4, S=2048, D=1024, H=16, HD=64, M = B*S = 8192.

typedef unsigned short ushortT;
typedef __attribute__((ext_vector_type(8))) __bf16 bf16x8;
typedef __attribute__((ext_vector_type(4))) float f32x4;
typedef __attribute__((ext_vector_type(16))) float f32x16;
typedef __attribute__((ext_vector_type(8))) unsigned short ushort8;
typedef __attribute__((ext_vector_type(4))) unsigned short ushort4v;

__device__ __forceinline__ unsigned short f2bf(float f) {
  union { float f; unsigned u; } x; x.f = f;
  unsigned r = (x.u + 0x7FFFu + ((x.u >> 16) & 1u)) >> 16;  // RNE
  return (unsigned short)r;
}

// packed f32x2 -> bf16x2 (RNE), dst[15:0]=lo, dst[31:16]=hi
__device__ __forceinline__ unsigned cvtpk_bf16(float lo, float hi) {
  unsigned r;
  asm("v_cvt_pk_bf16_f32 %0, %1, %2" : "=v"(r) : "v"(lo), "v"(hi));
  return r;
}

__device__ __forceinline__ void load_lds16(const void* g, void* l) {
  __builtin_amdgcn_global_load_lds(
      (const __attribute__((address_space(1))) void*)g,
      (__attribute__((address_space(3))) void*)l, 16, 0, 0);
}

__device__ __forceinline__ f32x4 mfma16(bf16x8 a, bf16x8 b, f32x4 c) {
  return __builtin_amdgcn_mfma_f32_16x16x32_bf16(a, b, c, 0, 0, 0);
}
__device__ __forceinline__ f32x16 mfma32(bf16x8 a, bf16x8 b, f32x16 c) {
  return __builtin_amdgcn_mfma_f32_32x32x16_bf16(a, b, c, 0, 0, 0);
}

// ---------------- f32 -> bf16 convert, weights only (4 x 1M elems) ---------
__global__ __launch_bounds__(256) void k_cvtw(const float* __restrict__ w0,
                                              const float* __restrict__ w1,
                                              const float* __restrict__ w2,
                                              const float* __restrict__ w3,
                                              ushortT* __restrict__ o0,
                                              ushortT* __restrict__ o1,
                                              ushortT* __restrict__ o2,
                                              ushortT* __restrict__ o3) {
  int z = blockIdx.z;
  const float* in = (z == 0) ? w0 : (z == 1) ? w1 : (z == 2) ? w2 : w3;
  ushortT* out = (z == 0) ? o0 : (z == 1) ? o1 : (z == 2) ? o2 : o3;
  int i = blockIdx.x * 256 + threadIdx.x;
  const float4* p = (const float4*)in;
  float4 u = p[(size_t)i * 2];
  float4 v = p[(size_t)i * 2 + 1];
  ushort8 o;
  o[0] = f2bf(u.x); o[1] = f2bf(u.y); o[2] = f2bf(u.z); o[3] = f2bf(u.w);
  o[4] = f2bf(v.x); o[5] = f2bf(v.y); o[6] = f2bf(v.z); o[7] = f2bf(v.w);
  *(ushort8*)(out + (size_t)i * 8) = o;
}

// ---------------- GEMM: C[m,n] = sum_k A[m,k]*W[n,k] (+epilogues) ------
// r10 2-phase structure (proven 195us total), ONE new variable: A-tile is
// reg-staged with fused f32->bf16 (T14 split: global loads ISSUED before the
// MFMA phase, cvt+ds_write AFTER it -> HBM latency hides under compute).
// Kills the separate x/y cvt pass (~15us). W stays bf16 via tiny k_cvtw
// (keeps per-XCD L2 set at 4MB). Mode 3 A (ctx bf16) = reg-copy variant.
// LDS layout/swizzle/readers byte-identical to r10 (pre-swizzled source).
// mode 0: Q=(x@Wq^T+bq)*c1  1: K=y@Wk^T+bk  2: V->[B,H,HD,S]  3: H=ctx@Wd^T+bd+x
__global__ __launch_bounds__(512, 4) void k_gemm(
    const float* __restrict__ xf, const float* __restrict__ yf,
    const ushortT* __restrict__ wq, const ushortT* __restrict__ wk,
    const ushortT* __restrict__ wv, const ushortT* __restrict__ wd,
    const float* __restrict__ bq, const float* __restrict__ bk,
    const float* __restrict__ bv, const float* __restrict__ bd,
    const ushortT* __restrict__ ctx, const float* __restrict__ xres,
    ushortT* __restrict__ Qo, ushortT* __restrict__ Ko,
    ushortT* __restrict__ Vt, float* __restrict__ Ho, int mode_base) {
  __shared__ ushortT lA[2][128 * 64];
  __shared__ ushortT lB[2][128 * 64];
  const int t = threadIdx.x;
  const int lane = t & 63;
  const int w = t >> 6;               // 0..7
  const int wm = w >> 1, wn = w & 1;  // 4 x 2 wave grid
  const int mode = mode_base + blockIdx.z;
  // T1 XCD y-band swizzle: XCD c owns a 1024-row M band x all 8 n-cols.
  const int flat = blockIdx.x + (blockIdx.y << 3);
  const int xcd = flat & 7, j = flat >> 3;
  const int m0 = (xcd * 8 + (j >> 3)) * 128;
  const int n0 = (j & 7) * 128;

  const bool af32 = (mode != 3);
  const float* Afp = (mode == 1) ? yf : xf;
  const ushortT* W = (mode == 0) ? wq : (mode == 1 ? wk : (mode == 2 ? wv : wd));
  const float* bias = (mode == 0) ? bq : (mode == 1 ? bk : (mode == 2 ? bv : bd));

  f32x4 z = {0.f, 0.f, 0.f, 0.f};
  f32x4 acc[2][4];
#pragma unroll
  for (int i = 0; i < 2; ++i)
#pragma unroll
    for (int j2 = 0; j2 < 4; ++j2) acc[i][j2] = z;

  // staging precompute: dest = linear t*16 (+c*8192); source col pre-swizzled
  const int so = t * 16;
  const int srow = so >> 7;                       // 0..63 (128B rows)
  const int skb = (so & 127) ^ ((srow & 7) << 4); // swizzled byte col
  const int se = skb >> 1;                        // element index
  const float* Afsrc = Afp + (size_t)(m0 + srow) * 1024 + se;
  const ushortT* Absrc = ctx + (size_t)(m0 + srow) * 1024 + se;  // mode 3
  const ushortT* wsrc = W + (size_t)(n0 + srow) * 1024 + se;

  float4 ar[2][2];
  ushort8 ab[2];

#define AISSUE(k0)                                                          \
  do {                                                                     \
    _Pragma("unroll")                                                      \
    for (int c = 0; c < 2; ++c) {                                          \
      if (af32) {                                                          \
        const float4* pa = (const float4*)(Afsrc + (k0) + c * 65536);      \
        ar[c][0] = pa[0];                                                  \
        ar[c][1] = pa[1];                                                  \
      } else {                                                             \
        ab[c] = *(const ushort8*)(Absrc + (k0) + c * 65536);               \
      }                                                                    \
    }                                                                      \
  } while (0)

#define AWRITE(buf)                                                        \
  do {                                                                     \
    _Pragma("unroll")                                                      \
    for (int c = 0; c < 2; ++c) {                                          \
      ushort8 o;                                                           \
      if (af32) {                                                          \
        unsigned w0 = cvtpk_bf16(ar[c][0].x, ar[c][0].y);                  \
        unsigned w1 = cvtpk_bf16(ar[c][0].z, ar[c][0].w);                  \
        unsigned w2 = cvtpk_bf16(ar[c][1].x, ar[c][1].y);                  \
        unsigned w3 = cvtpk_bf16(ar[c][1].z, ar[c][1].w);                  \
        o[0] = (unsigned short)w0; o[1] = (unsigned short)(w0 >> 16);      \
        o[2] = (unsigned short)w1; o[3] = (unsigned short)(w1 >> 16);      \
        o[4] = (unsigned short)w2; o[5] = (unsigned short)(w2 >> 16);      \
        o[6] = (unsigned short)w3; o[7] = (unsigned short)(w3 >> 16);      \
      } else {                                                             \
        o = ab[c];                                                         \
      }                                                                    \
      *(ushort8*)((char*)&lA[buf][0] + c * 8192 + t * 16) = o;             \
    }                                                                      \
  } while (0)

#define BSTAGE(buf, k0)                                                    \
  do {                                                                     \
    _Pragma("unroll")                                                      \
    for (int c = 0; c < 2; ++c)                                            \
      load_lds16(wsrc + (k0) + (size_t)c * 64 * 1024,                      \
                 (char*)&lB[buf][0] + c * 8192 + t * 16);                  \
  } while (0)

  // prologue: stage tile 0 fully, publish
  AISSUE(0);
  BSTAGE(0, 0);
  AWRITE(0);
  __syncthreads();
  int cur = 0;
  for (int k0 = 0; k0 < 1024; k0 += 64) {
    const bool pf = (k0 + 64 < 1024);
    if (pf) {
      AISSUE(k0 + 64);        // f32 loads in flight across the MFMA phase
      BSTAGE(cur ^ 1, k0 + 64);
    }
#pragma unroll
    for (int kk = 0; kk < 2; ++kk) {
      bf16x8 af[2], bfr[4];
#pragma unroll
      for (int i = 0; i < 2; ++i) {
        int arow = wm * 32 + i * 16 + (lane & 15);
        int ak = ((kk * 32 + (lane >> 4) * 8) * 2) ^ ((arow & 7) << 4);
        af[i] = *(const bf16x8*)((const char*)&lA[cur][0] + arow * 128 + ak);
      }
#pragma unroll
      for (int i = 0; i < 4; ++i) {
        int brow = wn * 64 + i * 16 + (lane & 15);
        int bk2 = ((kk * 32 + (lane >> 4) * 8) * 2) ^ ((brow & 7) << 4);
        bfr[i] = *(const bf16x8*)((const char*)&lB[cur][0] + brow * 128 + bk2);
      }
      __builtin_amdgcn_s_setprio(1);
#pragma unroll
      for (int i = 0; i < 2; ++i)
#pragma unroll
        for (int j2 = 0; j2 < 4; ++j2)
          acc[i][j2] = mfma16(af[i], bfr[j2], acc[i][j2]);
      __builtin_amdgcn_s_setprio(0);
    }
    if (pf) AWRITE(cur ^ 1);  // cvt + ds_write after compute (T14 late-write)
    __syncthreads();
    cur ^= 1;
  }
#undef AISSUE
#undef AWRITE
#undef BSTAGE

  const int cm = wm * 32 + (lane >> 4) * 4;  // + mi*16 + r
  const int cn = wn * 64 + (lane & 15);      // + ni*16
  if (mode == 3) {
#pragma unroll
    for (int mi = 0; mi < 2; ++mi)
#pragma unroll
      for (int ni = 0; ni < 4; ++ni) {
        int n = n0 + cn + ni * 16;
        float bn = bias[n];
#pragma unroll
        for (int r = 0; r < 4; ++r) {
          int m = m0 + cm + mi * 16 + r;
          Ho[(size_t)m * 1024 + n] =
              acc[mi][ni][r] + bn + xres[(size_t)m * 1024 + n];
        }
      }
  } else if (mode == 2) {
#pragma unroll
    for (int mi = 0; mi < 2; ++mi)
#pragma unroll
      for (int ni = 0; ni < 4; ++ni) {
        int n = n0 + cn + ni * 16;
        int hh = n >> 6, hd = n & 63;
        float bn = bias[n];
        int m_ = m0 + cm + mi * 16;
        int b = m_ >> 11, s = m_ & 2047;
        ushort4v pk;
#pragma unroll
        for (int r = 0; r < 4; ++r) pk[r] = f2bf(acc[mi][ni][r] + bn);
        *(ushort4v*)&Vt[(((size_t)(b * 16 + hh) * 64 + hd) << 11) + s] = pk;
      }
  } else {
    ushortT* O = (mode == 0) ? Qo : Ko;
    // mode 0: fold softmax temperature (1/8)*log2(e) into Q.
    const float qs = (mode == 0) ? 0.18033688011112042f : 1.0f;
#pragma unroll
    for (int mi = 0; mi < 2; ++mi)
#pragma unroll
      for (int ni = 0; ni < 4; ++ni) {
        int n = n0 + cn + ni * 16;
        int hh = n >> 6, hd = n & 63;
        float bn = bias[n];
#pragma unroll
        for (int r = 0; r < 4; ++r) {
          int m = m0 + cm + mi * 16 + r;
          int b = m >> 11, s = m & 2047;
          O[(((size_t)(b * 16 + hh) * 2048 + s) << 6) + hd] =
              f2bf((acc[mi][ni][r] + bn) * qs);
        }
      }
  }
}

// ---------------- Flash attention, 4-wave swapped-QK^T 32x32 ----------------
// grid: 1024 blocks (16 qtiles x 64 bh), XCD-swizzled; block 256 = 4 waves.
// Each wave owns 32 q-rows; KV tile = 64 keys, double-buffered in LDS.
// Q prescaled by (1/8)*log2(e) in k_gemm -> p = exp2(sc) raw.
// Row-sums via MFMA with ones-B: accL[r] = sum_k P[k][q=qm(r,hi)].
__global__ __launch_bounds__(256, 4) void k_attn(const ushortT* __restrict__ Q,
                                                 const ushortT* __restrict__ K,
                                                 const ushortT* __restrict__ Vt,
                                                 ushortT* __restrict__ ctx) {
  __shared__ ushortT lK[2][4096];  // [buf][64 keys][64 d], 128B rows, XOR-swz
  __shared__ ushortT lV[2][4096];  // [buf][64 d][64 keys], 128B rows, XOR-swz
  const int t = threadIdx.x, lane = t & 63, w = t >> 6;
  const int hi = lane >> 5, l31 = lane & 31;
  const int i0 = blockIdx.x;
  const int xcd = i0 & 7, j0 = i0 >> 3;              // round-robin XCD map
  const int bh = xcd * 8 + (j0 >> 4);                // 8 bh per XCD -> L2-fit
  const int qt = j0 & 15;
  const int q0 = qt * 128 + w * 32;

  const ushortT* Qb = Q + ((size_t)bh * 2048 + q0) * 64;
  const ushortT* Kb = K + (size_t)bh * 2048 * 64;
  const ushortT* Vb = Vt + (size_t)bh * 64 * 2048;

  // Q fragments (B-operand): Q[q=l31, d = dc*16 + hi*8 + j]
  bf16x8 qf[4];
#pragma unroll
  for (int dc = 0; dc < 4; ++dc)
    qf[dc] = *(const bf16x8*)(Qb + l31 * 64 + dc * 16 + hi * 8);

  // ones B-operand for row-sum MFMA
  union { unsigned short us[8]; bf16x8 v; } ones_u;
#pragma unroll
  for (int i = 0; i < 8; ++i) ones_u.us[i] = 0x3F80;

  f32x16 accO0, accO1, accL;
#pragma unroll
  for (int i = 0; i < 16; ++i) { accO0[i] = 0.f; accO1[i] = 0.f; accL[i] = 0.f; }

  // staging: linear LDS dest, pre-swizzled global source (rule #21)
  const int srow = t >> 3;                 // 0..31
  const int scolb = ((t & 7) * 16) ^ ((srow & 7) << 4);
  const ushortT* ksrc = Kb + srow * 64 + (scolb >> 1);
  const ushortT* vsrc = Vb + (size_t)srow * 2048 + (scolb >> 1);
  const int swz = (lane & 7) << 4;
  const int hs = (hi * 16) ^ swz;
  const int krowb = l31 * 128;

#define STAGE(buf, kk)                                                        \
  do {                                                                        \
    load_lds16(ksrc + (size_t)(kk) * 64, (char*)&lK[buf][0] + w * 1024);      \
    load_lds16(ksrc + 2048 + (size_t)(kk) * 64,                               \
               (char*)&lK[buf][0] + 4096 + w * 1024);                         \
    load_lds16(vsrc + (kk), (char*)&lV[buf][0] + w * 1024);                   \
    load_lds16(vsrc + 65536 + (kk), (char*)&lV[buf][0] + 4096 + w * 1024);    \
  } while (0)

  STAGE(0, 0);
  __syncthreads();
  int cur = 0;
  for (int k0 = 0; k0 < 2048; k0 += 64) {
    if (k0 + 64 < 2048) STAGE(cur ^ 1, k0 + 64);
    const char* lKc = (const char*)&lK[cur][0];
    const char* lVc = (const char*)&lV[cur][0];
#pragma unroll
    for (int kb = 0; kb < 2; ++kb) {
      // ---- QK^T (swapped): sc[r] = S[krow(r,hi), q=l31]
      f32x16 sc;
#pragma unroll
      for (int i = 0; i < 16; ++i) sc[i] = 0.f;
      __builtin_amdgcn_s_setprio(1);
#pragma unroll
      for (int dc = 0; dc < 4; ++dc) {
        bf16x8 kf = *(const bf16x8*)(lKc + kb * 4096 + krowb + ((dc * 32) ^ hs));
        sc = mfma32(kf, qf[dc], sc);
      }
      __builtin_amdgcn_s_setprio(0);
      // ---- softmax numerator: p = exp2(sc) (raw v_exp_f32, no ocml fixup)
      float p[16];
#pragma unroll
      for (int r = 0; r < 16; ++r) p[r] = __builtin_amdgcn_exp2f(sc[r]);
      // ---- pack P -> bf16 words (cvt_pk); exchange halves (permlane32_swap)
      union { unsigned u[4]; bf16x8 v; } pa0, pa1;
#pragma unroll
      for (int i = 0; i < 4; ++i) {
        int base = (i >> 1) * 8 + (i & 1) * 2;  // 0,2,8,10
        unsigned a = cvtpk_bf16(p[base], p[base + 1]);        // keys 4hi+b..
        unsigned b = cvtpk_bf16(p[base + 4], p[base + 5]);    // keys 8+4hi+b..
        asm("v_permlane32_swap_b32 %0, %1" : "+v"(a), "+v"(b));
        if (i >> 1) { pa1.u[i & 1] = a; pa1.u[2 + (i & 1)] = b; }
        else        { pa0.u[i & 1] = a; pa0.u[2 + (i & 1)] = b; }
      }
      // ---- PV + row-sum: accO[nb] += P x V ; accL += P x ones
      __builtin_amdgcn_s_setprio(1);
#pragma unroll
      for (int nb = 0; nb < 2; ++nb) {
        const char* vrow = lVc + (nb * 32 + l31) * 128;
        bf16x8 vf0 = *(const bf16x8*)(vrow + ((kb * 64) ^ hs));
        bf16x8 vf1 = *(const bf16x8*)(vrow + ((kb * 64 + 32) ^ hs));
        f32x16& ao = nb ? accO1 : accO0;
        ao = mfma32(pa0.v, vf0, ao);
        ao = mfma32(pa1.v, vf1, ao);
      }
      accL = mfma32(pa0.v, ones_u.v, accL);
      accL = mfma32(pa1.v, ones_u.v, accL);
      __builtin_amdgcn_s_setprio(0);
    }
    __syncthreads();
    cur ^= 1;
  }
#undef STAGE

  // epilogue: O[q,d] = accO/accL -> ctx[B,S,D] bf16
  int b = bh >> 4, hh = bh & 15;
  ushortT* cb = ctx + ((size_t)(b * 2048 + q0)) * 1024 + hh * 64;
#pragma unroll
  for (int r = 0; r < 16; ++r) {
    int qm = (r & 3) + 8 * (r >> 2) + 4 * hi;
    float lr = 1.0f / accL[r];
    size_t rb = (size_t)qm * 1024;
    cb[rb + l31] = f2bf(accO0[r] * lr);
    cb[rb + 32 + l31] = f2bf(accO1[r] * lr);
  }
}

// ---------------- LayerNorm (one row per block) ----------------
__global__ __launch_bounds__(256) void k_ln(const float* __restrict__ Hi,
                                            const float* __restrict__ gamma,
                                            const float* __restrict__ beta,
                                            float* __restrict__ out) {
  const int row = blockIdx.x, t = threadIdx.x, lane = t & 63, w = t >> 6;
  const float4* hp = (const float4*)(Hi + (size_t)row * 1024);
  float4 v = hp[t];
  float s1 = v.x + v.y + v.z + v.w;
  float s2 = v.x * v.x + v.y * v.y + v.z * v.z + v.w * v.w;
#pragma unroll
  for (int off = 1; off < 64; off <<= 1) {
    s1 += __shfl_xor(s1, off);
    s2 += __shfl_xor(s2, off);
  }
  __shared__ float red[8];
  if (lane == 0) { red[w] = s1; red[4 + w] = s2; }
  __syncthreads();
  s1 = red[0] + red[1] + red[2] + red[3];
  s2 = red[4] + red[5] + red[6] + red[7];
  float u = s1 * (1.f / 1024.f);
  float var = s2 * (1.f / 1024.f) - u * u;
  float rstd = rsqrtf(var + 1e-12f);
  float4 g = ((const float4*)gamma)[t];
  float4 bb = ((const float4*)beta)[t];
  float4 oo;
  oo.x = (v.x - u) * rstd * g.x + bb.x;
  oo.y = (v.y - u) * rstd * g.y + bb.y;
  oo.z = (v.z - u) * rstd * g.z + bb.z;
  oo.w = (v.w - u) * rstd * g.w + bb.w;
  ((float4*)(out + (size_t)row * 1024))[t] = oo;
}

extern "C" void kernel_launch(void* const* d_in, const int* in_sizes, int n_in,
                              void* d_out, int out_size, void* d_ws,
                              size_t ws_size, hipStream_t stream) {
  const float* x = (const float*)d_in[0];
  const float* y = (const float*)d_in[1];
  const float* Wq = (const float*)d_in[2];
  const float* bq = (const float*)d_in[3];
  const float* Wk = (const float*)d_in[4];
  const float* bk = (const float*)d_in[5];
  const float* Wv = (const float*)d_in[6];
  const float* bv = (const float*)d_in[7];
  const float* Wd = (const float*)d_in[8];
  const float* bd = (const float*)d_in[9];
  const float* gamma = (const float*)d_in[10];
  const float* beta = (const float*)d_in[11];

  char* ws = (char*)d_ws;
  ushortT* wqb = (ushortT*)(ws + 33554432);   // 2 MiB each
  ushortT* wkb = (ushortT*)(ws + 35651584);
  ushortT* wvb = (ushortT*)(ws + 37748736);
  ushortT* wdb = (ushortT*)(ws + 39845888);
  ushortT* Qb = (ushortT*)(ws + 41943040);    // 16 MiB
  ushortT* Kb = (ushortT*)(ws + 58720256);    // 16 MiB
  ushortT* Vtb = (ushortT*)(ws + 75497472);   // 16 MiB
  ushortT* ctx = (ushortT*)(ws + 92274688);   // 16 MiB
  float* Hbuf = (float*)(ws + 0);  // 32 MiB (region unused otherwise now)

  k_cvtw<<<dim3(512, 1, 4), 256, 0, stream>>>(Wq, Wk, Wv, Wd, wqb, wkb, wvb,
                                              wdb);

  k_gemm<<<dim3(8, 64, 3), 512, 0, stream>>>(x, y, wqb, wkb, wvb, wdb, bq, bk,
                                             bv, bd, ctx, x, Qb, Kb, Vtb, Hbuf,
                                             0);
  k_attn<<<1024, 256, 0, stream>>>(Qb, Kb, Vtb, ctx);
  k_gemm<<<dim3(8, 64, 1), 512, 0, stream>>>(x, y, wqb, wkb, wvb, wdb, bq, bk,
                                             bv, bd, ctx, x, Qb, Kb, Vtb, Hbuf,
                                             3);
  k_ln<<<8192, 256, 0, stream>>>(Hbuf, gamma, beta, (float*)d_out);
}

// Round 14
// 195.105 us; speedup vs baseline: 1.3051x; 1.1690x over previous
//
#include <hip/hip_runtime.h>
#include <hip/hip_bf16.h>
#include <stdint.h>

// Problem constants: B=4, S=2048, D=1024, H=16, HD=64, M = B*S = 8192.

typedef unsigned short ushortT;
typedef __attribute__((ext_vector_type(8))) __bf16 bf16x8;
typedef __attribute__((ext_vector_type(4))) float f32x4;
typedef __attribute__((ext_vector_type(16))) float f32x16;
typedef __attribute__((ext_vector_type(8))) unsigned short ushort8;
typedef __attribute__((ext_vector_type(4))) unsigned short ushort4v;

__device__ __forceinline__ unsigned short f2bf(float f) {
  union { float f; unsigned u; } x; x.f = f;
  unsigned r = (x.u + 0x7FFFu + ((x.u >> 16) & 1u)) >> 16;  // RNE
  return (unsigned short)r;
}

__device__ __forceinline__ float bf2f(ushortT u) {
  union { unsigned u; float f; } x;
  x.u = ((unsigned)u) << 16;
  return x.f;
}

// packed f32x2 -> bf16x2 (RNE), dst[15:0]=lo, dst[31:16]=hi
__device__ __forceinline__ unsigned cvtpk_bf16(float lo, float hi) {
  unsigned r;
  asm("v_cvt_pk_bf16_f32 %0, %1, %2" : "=v"(r) : "v"(lo), "v"(hi));
  return r;
}

__device__ __forceinline__ void load_lds16(const void* g, void* l) {
  __builtin_amdgcn_global_load_lds(
      (const __attribute__((address_space(1))) void*)g,
      (__attribute__((address_space(3))) void*)l, 16, 0, 0);
}

__device__ __forceinline__ f32x4 mfma16(bf16x8 a, bf16x8 b, f32x4 c) {
  return __builtin_amdgcn_mfma_f32_16x16x32_bf16(a, b, c, 0, 0, 0);
}
__device__ __forceinline__ f32x16 mfma32(bf16x8 a, bf16x8 b, f32x16 c) {
  return __builtin_amdgcn_mfma_f32_32x32x16_bf16(a, b, c, 0, 0, 0);
}

// ---------------- f32 -> bf16 convert, all 6 tensors in one launch ---------
__global__ __launch_bounds__(256) void k_cvt_all(
    const float* __restrict__ x, const float* __restrict__ y,
    const float* __restrict__ w0, const float* __restrict__ w1,
    const float* __restrict__ w2, const float* __restrict__ w3,
    ushortT* __restrict__ ox, ushortT* __restrict__ oy,
    ushortT* __restrict__ o0, ushortT* __restrict__ o1,
    ushortT* __restrict__ o2, ushortT* __restrict__ o3) {
  int b = blockIdx.x;
  const float* in;
  ushortT* out;
  int blk;
  if (b < 4096) {
    in = x; out = ox; blk = b;
  } else if (b < 8192) {
    in = y; out = oy; blk = b - 4096;
  } else {
    int z = (b - 8192) >> 9;
    blk = (b - 8192) & 511;
    in = (z == 0) ? w0 : (z == 1) ? w1 : (z == 2) ? w2 : w3;
    out = (z == 0) ? o0 : (z == 1) ? o1 : (z == 2) ? o2 : o3;
  }
  int i = blk * 256 + threadIdx.x;
  const float4* p = (const float4*)in;
  float4 u = p[(size_t)i * 2];
  float4 v = p[(size_t)i * 2 + 1];
  ushort8 o;
  o[0] = f2bf(u.x); o[1] = f2bf(u.y); o[2] = f2bf(u.z); o[3] = f2bf(u.w);
  o[4] = f2bf(v.x); o[5] = f2bf(v.y); o[6] = f2bf(v.z); o[7] = f2bf(v.w);
  *(ushort8*)(out + (size_t)i * 8) = o;
}

// ---------------- GEMM: C[m,n] = sum_k A[m,k]*W[n,k] (+epilogues) ------
// 512 threads = 8 waves (4x2 wave-grid, 32x64 sub-tile each), 128^2 tile,
// T3-min 2-phase double-buffer: STAGE(next) before compute(cur), ONE
// __syncthreads per K-step. 64KB LDS -> 2 blocks/CU -> 4 waves/SIMD.
// (r10 proven structure; r11-r13 structural experiments all regressed.)
// mode 0: Q = (x@Wq^T + bq) * c1 -> [B,H,S,HD] bf16  (softmax temp prescale)
// mode 1: K = y@Wk^T + bk  -> [B,H,S,HD] bf16
// mode 2: V = x@Wv^T + bv  -> [B,H,HD,S] bf16 (transposed)
// mode 3: H = ctx@Wd^T + bd + xbf -> [M,D] f32 (bf16 residual, saves 16MB)
__global__ __launch_bounds__(512, 4) void k_gemm(
    const ushortT* __restrict__ xbf, const ushortT* __restrict__ ybf,
    const ushortT* __restrict__ wq, const ushortT* __restrict__ wk,
    const ushortT* __restrict__ wv, const ushortT* __restrict__ wd,
    const float* __restrict__ bq, const float* __restrict__ bk,
    const float* __restrict__ bv, const float* __restrict__ bd,
    const ushortT* __restrict__ ctx, const float* __restrict__ xres,
    ushortT* __restrict__ Qo, ushortT* __restrict__ Ko,
    ushortT* __restrict__ Vt, float* __restrict__ Ho, int mode_base) {
  __shared__ ushortT lA[2][128 * 64];
  __shared__ ushortT lB[2][128 * 64];
  const int t = threadIdx.x;
  const int lane = t & 63;
  const int w = t >> 6;            // 0..7
  const int wm = w >> 1, wn = w & 1;  // 4 x 2 wave grid
  const int mode = mode_base + blockIdx.z;
  // T1 XCD y-band swizzle: XCD c gets y in [8c, 8c+8), all 8 x per y.
  const int flat = blockIdx.x + (blockIdx.y << 3);
  const int xcd = flat & 7, j = flat >> 3;
  const int m0 = (xcd * 8 + (j >> 3)) * 128;
  const int n0 = (j & 7) * 128;

  const ushortT* A = (mode == 1) ? ybf : (mode == 3 ? ctx : xbf);
  const ushortT* W = (mode == 0) ? wq : (mode == 1 ? wk : (mode == 2 ? wv : wd));
  const float* bias = (mode == 0) ? bq : (mode == 1 ? bk : (mode == 2 ? bv : bd));

  f32x4 z = {0.f, 0.f, 0.f, 0.f};
  f32x4 acc[2][4];
#pragma unroll
  for (int i = 0; i < 2; ++i)
#pragma unroll
    for (int j2 = 0; j2 < 4; ++j2) acc[i][j2] = z;

  // staging precompute (linear LDS dest; pre-swizzled global source)
  const int so = t * 16;                          // 0..8176
  const int srow = so >> 7;                       // 0..63 (128B per row)
  const int skb = (so & 127) ^ ((srow & 7) << 4); // pre-swizzled source col
  const ushortT* asrc = A + (size_t)(m0 + srow) * 1024 + (skb >> 1);
  const ushortT* wsrc = W + (size_t)(n0 + srow) * 1024 + (skb >> 1);

  // 512 thr x 16B = 8KB per c-iter; c<2 covers the 16KB (128x64 bf16) tile.
#define GSTAGE(buf, k0)                                                     \
  do {                                                                      \
    _Pragma("unroll")                                                       \
    for (int c = 0; c < 2; ++c) {                                           \
      load_lds16(asrc + (k0) + (size_t)c * 64 * 1024,                       \
                 (char*)&lA[buf][0] + c * 8192 + t * 16);                   \
      load_lds16(wsrc + (k0) + (size_t)c * 64 * 1024,                       \
                 (char*)&lB[buf][0] + c * 8192 + t * 16);                   \
    }                                                                       \
  } while (0)

  GSTAGE(0, 0);
  __syncthreads();
  int cur = 0;
  for (int k0 = 0; k0 < 1024; k0 += 64) {
    if (k0 + 64 < 1024) GSTAGE(cur ^ 1, k0 + 64);
#pragma unroll
    for (int kk = 0; kk < 2; ++kk) {
      bf16x8 af[2], bfr[4];
#pragma unroll
      for (int i = 0; i < 2; ++i) {
        int arow = wm * 32 + i * 16 + (lane & 15);
        int ak = ((kk * 32 + (lane >> 4) * 8) * 2) ^ ((arow & 7) << 4);
        af[i] = *(const bf16x8*)((const char*)&lA[cur][0] + arow * 128 + ak);
      }
#pragma unroll
      for (int i = 0; i < 4; ++i) {
        int brow = wn * 64 + i * 16 + (lane & 15);
        int bk2 = ((kk * 32 + (lane >> 4) * 8) * 2) ^ ((brow & 7) << 4);
        bfr[i] = *(const bf16x8*)((const char*)&lB[cur][0] + brow * 128 + bk2);
      }
      __builtin_amdgcn_s_setprio(1);
#pragma unroll
      for (int i = 0; i < 2; ++i)
#pragma unroll
        for (int j2 = 0; j2 < 4; ++j2)
          acc[i][j2] = mfma16(af[i], bfr[j2], acc[i][j2]);
      __builtin_amdgcn_s_setprio(0);
    }
    __syncthreads();
    cur ^= 1;
  }
#undef GSTAGE

  const int cm = wm * 32 + (lane >> 4) * 4;  // + mi*16 + r
  const int cn = wn * 64 + (lane & 15);      // + ni*16
  if (mode == 3) {
#pragma unroll
    for (int mi = 0; mi < 2; ++mi)
#pragma unroll
      for (int ni = 0; ni < 4; ++ni) {
        int n = n0 + cn + ni * 16;
        float bn = bias[n];
#pragma unroll
        for (int r = 0; r < 4; ++r) {
          int m = m0 + cm + mi * 16 + r;
          Ho[(size_t)m * 1024 + n] =
              acc[mi][ni][r] + bn + bf2f(xbf[(size_t)m * 1024 + n]);
        }
      }
  } else if (mode == 2) {
#pragma unroll
    for (int mi = 0; mi < 2; ++mi)
#pragma unroll
      for (int ni = 0; ni < 4; ++ni) {
        int n = n0 + cn + ni * 16;
        int hh = n >> 6, hd = n & 63;
        float bn = bias[n];
        int m_ = m0 + cm + mi * 16;
        int b = m_ >> 11, s = m_ & 2047;
        ushort4v pk;
#pragma unroll
        for (int r = 0; r < 4; ++r) pk[r] = f2bf(acc[mi][ni][r] + bn);
        *(ushort4v*)&Vt[(((size_t)(b * 16 + hh) * 64 + hd) << 11) + s] = pk;
      }
  } else {
    ushortT* O = (mode == 0) ? Qo : Ko;
    // mode 0: fold softmax temperature (1/8)*log2(e) into Q so the attention
    // kernel computes p = exp2(sc) with no per-score multiply.
    const float qs = (mode == 0) ? 0.18033688011112042f : 1.0f;
#pragma unroll
    for (int mi = 0; mi < 2; ++mi)
#pragma unroll
      for (int ni = 0; ni < 4; ++ni) {
        int n = n0 + cn + ni * 16;
        int hh = n >> 6, hd = n & 63;
        float bn = bias[n];
#pragma unroll
        for (int r = 0; r < 4; ++r) {
          int m = m0 + cm + mi * 16 + r;
          int b = m >> 11, s = m & 2047;
          O[(((size_t)(b * 16 + hh) * 2048 + s) << 6) + hd] =
              f2bf((acc[mi][ni][r] + bn) * qs);
        }
      }
  }
}

// ---------------- Flash attention, 4-wave swapped-QK^T 32x32 ----------------
// grid: 1024 blocks (16 qtiles x 64 bh), XCD-swizzled; block 256 = 4 waves.
// Each wave owns 32 q-rows; KV tile = 64 keys, double-buffered in LDS.
// Q prescaled by (1/8)*log2(e) in k_gemm -> p = exp2(sc) raw.
// Row-sums via MFMA with ones-B: accL[r] = sum_k P[k][q=qm(r,hi)].
__global__ __launch_bounds__(256, 4) void k_attn(const ushortT* __restrict__ Q,
                                                 const ushortT* __restrict__ K,
                                                 const ushortT* __restrict__ Vt,
                                                 ushortT* __restrict__ ctx) {
  __shared__ ushortT lK[2][4096];  // [buf][64 keys][64 d], 128B rows, XOR-swz
  __shared__ ushortT lV[2][4096];  // [buf][64 d][64 keys], 128B rows, XOR-swz
  const int t = threadIdx.x, lane = t & 63, w = t >> 6;
  const int hi = lane >> 5, l31 = lane & 31;
  const int i0 = blockIdx.x;
  const int xcd = i0 & 7, j0 = i0 >> 3;              // round-robin XCD map
  const int bh = xcd * 8 + (j0 >> 4);                // 8 bh per XCD -> L2-fit
  const int qt = j0 & 15;
  const int q0 = qt * 128 + w * 32;

  const ushortT* Qb = Q + ((size_t)bh * 2048 + q0) * 64;
  const ushortT* Kb = K + (size_t)bh * 2048 * 64;
  const ushortT* Vb = Vt + (size_t)bh * 64 * 2048;

  // Q fragments (B-operand): Q[q=l31, d = dc*16 + hi*8 + j]
  bf16x8 qf[4];
#pragma unroll
  for (int dc = 0; dc < 4; ++dc)
    qf[dc] = *(const bf16x8*)(Qb + l31 * 64 + dc * 16 + hi * 8);

  // ones B-operand for row-sum MFMA
  union { unsigned short us[8]; bf16x8 v; } ones_u;
#pragma unroll
  for (int i = 0; i < 8; ++i) ones_u.us[i] = 0x3F80;

  f32x16 accO0, accO1, accL;
#pragma unroll
  for (int i = 0; i < 16; ++i) { accO0[i] = 0.f; accO1[i] = 0.f; accL[i] = 0.f; }

  // staging: linear LDS dest, pre-swizzled global source (rule #21)
  const int srow = t >> 3;                 // 0..31
  const int scolb = ((t & 7) * 16) ^ ((srow & 7) << 4);
  const ushortT* ksrc = Kb + srow * 64 + (scolb >> 1);
  const ushortT* vsrc = Vb + (size_t)srow * 2048 + (scolb >> 1);
  const int swz = (lane & 7) << 4;
  const int hs = (hi * 16) ^ swz;
  const int krowb = l31 * 128;

#define STAGE(buf, kk)                                                        \
  do {                                                                        \
    load_lds16(ksrc + (size_t)(kk) * 64, (char*)&lK[buf][0] + w * 1024);      \
    load_lds16(ksrc + 2048 + (size_t)(kk) * 64,                               \
               (char*)&lK[buf][0] + 4096 + w * 1024);                         \
    load_lds16(vsrc + (kk), (char*)&lV[buf][0] + w * 1024);                   \
    load_lds16(vsrc + 65536 + (kk), (char*)&lV[buf][0] + 4096 + w * 1024);    \
  } while (0)

  STAGE(0, 0);
  __syncthreads();
  int cur = 0;
  for (int k0 = 0; k0 < 2048; k0 += 64) {
    if (k0 + 64 < 2048) STAGE(cur ^ 1, k0 + 64);
    const char* lKc = (const char*)&lK[cur][0];
    const char* lVc = (const char*)&lV[cur][0];
#pragma unroll
    for (int kb = 0; kb < 2; ++kb) {
      // ---- QK^T (swapped): sc[r] = S[krow(r,hi), q=l31]
      f32x16 sc;
#pragma unroll
      for (int i = 0; i < 16; ++i) sc[i] = 0.f;
      __builtin_amdgcn_s_setprio(1);
#pragma unroll
      for (int dc = 0; dc < 4; ++dc) {
        bf16x8 kf = *(const bf16x8*)(lKc + kb * 4096 + krowb + ((dc * 32) ^ hs));
        sc = mfma32(kf, qf[dc], sc);
      }
      __builtin_amdgcn_s_setprio(0);
      // ---- softmax numerator: p = exp2(sc) (raw v_exp_f32, no ocml fixup)
      float p[16];
#pragma unroll
      for (int r = 0; r < 16; ++r) p[r] = __builtin_amdgcn_exp2f(sc[r]);
      // ---- pack P -> bf16 words (cvt_pk); exchange halves (permlane32_swap)
      union { unsigned u[4]; bf16x8 v; } pa0, pa1;
#pragma unroll
      for (int i = 0; i < 4; ++i) {
        int base = (i >> 1) * 8 + (i & 1) * 2;  // 0,2,8,10
        unsigned a = cvtpk_bf16(p[base], p[base + 1]);        // keys 4hi+b..
        unsigned b = cvtpk_bf16(p[base + 4], p[base + 5]);    // keys 8+4hi+b..
        asm("v_permlane32_swap_b32 %0, %1" : "+v"(a), "+v"(b));
        if (i >> 1) { pa1.u[i & 1] = a; pa1.u[2 + (i & 1)] = b; }
        else        { pa0.u[i & 1] = a; pa0.u[2 + (i & 1)] = b; }
      }
      // ---- PV + row-sum: accO[nb] += P x V ; accL += P x ones
      __builtin_amdgcn_s_setprio(1);
#pragma unroll
      for (int nb = 0; nb < 2; ++nb) {
        const char* vrow = lVc + (nb * 32 + l31) * 128;
        bf16x8 vf0 = *(const bf16x8*)(vrow + ((kb * 64) ^ hs));
        bf16x8 vf1 = *(const bf16x8*)(vrow + ((kb * 64 + 32) ^ hs));
        f32x16& ao = nb ? accO1 : accO0;
        ao = mfma32(pa0.v, vf0, ao);
        ao = mfma32(pa1.v, vf1, ao);
      }
      accL = mfma32(pa0.v, ones_u.v, accL);
      accL = mfma32(pa1.v, ones_u.v, accL);
      __builtin_amdgcn_s_setprio(0);
    }
    __syncthreads();
    cur ^= 1;
  }
#undef STAGE

  // epilogue: O[q,d] = accO/accL -> ctx[B,S,D] bf16
  int b = bh >> 4, hh = bh & 15;
  ushortT* cb = ctx + ((size_t)(b * 2048 + q0)) * 1024 + hh * 64;
#pragma unroll
  for (int r = 0; r < 16; ++r) {
    int qm = (r & 3) + 8 * (r >> 2) + 4 * hi;
    float lr = 1.0f / accL[r];
    size_t rb = (size_t)qm * 1024;
    cb[rb + l31] = f2bf(accO0[r] * lr);
    cb[rb + 32 + l31] = f2bf(accO1[r] * lr);
  }
}

// ---------------- LayerNorm (one row per block) ----------------
__global__ __launch_bounds__(256) void k_ln(const float* __restrict__ Hi,
                                            const float* __restrict__ gamma,
                                            const float* __restrict__ beta,
                                            float* __restrict__ out) {
  const int row = blockIdx.x, t = threadIdx.x, lane = t & 63, w = t >> 6;
  const float4* hp = (const float4*)(Hi + (size_t)row * 1024);
  float4 v = hp[t];
  float s1 = v.x + v.y + v.z + v.w;
  float s2 = v.x * v.x + v.y * v.y + v.z * v.z + v.w * v.w;
#pragma unroll
  for (int off = 1; off < 64; off <<= 1) {
    s1 += __shfl_xor(s1, off);
    s2 += __shfl_xor(s2, off);
  }
  __shared__ float red[8];
  if (lane == 0) { red[w] = s1; red[4 + w] = s2; }
  __syncthreads();
  s1 = red[0] + red[1] + red[2] + red[3];
  s2 = red[4] + red[5] + red[6] + red[7];
  float u = s1 * (1.f / 1024.f);
  float var = s2 * (1.f / 1024.f) - u * u;
  float rstd = rsqrtf(var + 1e-12f);
  float4 g = ((const float4*)gamma)[t];
  float4 bb = ((const float4*)beta)[t];
  float4 oo;
  oo.x = (v.x - u) * rstd * g.x + bb.x;
  oo.y = (v.y - u) * rstd * g.y + bb.y;
  oo.z = (v.z - u) * rstd * g.z + bb.z;
  oo.w = (v.w - u) * rstd * g.w + bb.w;
  ((float4*)(out + (size_t)row * 1024))[t] = oo;
}

extern "C" void kernel_launch(void* const* d_in, const int* in_sizes, int n_in,
                              void* d_out, int out_size, void* d_ws,
                              size_t ws_size, hipStream_t stream) {
  const float* x = (const float*)d_in[0];
  const float* y = (const float*)d_in[1];
  const float* Wq = (const float*)d_in[2];
  const float* bq = (const float*)d_in[3];
  const float* Wk = (const float*)d_in[4];
  const float* bk = (const float*)d_in[5];
  const float* Wv = (const float*)d_in[6];
  const float* bv = (const float*)d_in[7];
  const float* Wd = (const float*)d_in[8];
  const float* bd = (const float*)d_in[9];
  const float* gamma = (const float*)d_in[10];
  const float* beta = (const float*)d_in[11];

  char* ws = (char*)d_ws;
  ushortT* xbf = (ushortT*)(ws + 0);          // 16 MiB
  ushortT* ybf = (ushortT*)(ws + 16777216);   // 16 MiB
  ushortT* wqb = (ushortT*)(ws + 33554432);   // 2 MiB
  ushortT* wkb = (ushortT*)(ws + 35651584);
  ushortT* wvb = (ushortT*)(ws + 37748736);
  ushortT* wdb = (ushortT*)(ws + 39845888);
  ushortT* Qb = (ushortT*)(ws + 41943040);    // 16 MiB
  ushortT* Kb = (ushortT*)(ws + 58720256);    // 16 MiB
  ushortT* Vtb = (ushortT*)(ws + 75497472);   // 16 MiB
  ushortT* ctx = (ushortT*)(ws + 92274688);   // 16 MiB
  float* Hbuf = (float*)(ws + 109051904);     // 32 MiB (no aliasing w/ xbf now)

  k_cvt_all<<<10240, 256, 0, stream>>>(x, y, Wq, Wk, Wv, Wd, xbf, ybf, wqb,
                                       wkb, wvb, wdb);

  k_gemm<<<dim3(8, 64, 3), 512, 0, stream>>>(xbf, ybf, wqb, wkb, wvb, wdb, bq,
                                             bk, bv, bd, ctx, x, Qb, Kb, Vtb,
                                             Hbuf, 0);
  k_attn<<<1024, 256, 0, stream>>>(Qb, Kb, Vtb, ctx);
  k_gemm<<<dim3(8, 64, 1), 512, 0, stream>>>(xbf, ybf, wqb, wkb, wvb, wdb, bq,
                                             bk, bv, bd, ctx, x, Qb, Kb, Vtb,
                                             Hbuf, 3);
  k_ln<<<8192, 256, 0, stream>>>(Hbuf, gamma, beta, (float*)d_out);
}

// Round 15
// 190.879 us; speedup vs baseline: 1.3340x; 1.0221x over previous
//
#include <hip/hip_runtime.h>
#include <hip/hip_bf16.h>
#include <stdint.h>

// Problem constants: B=4, S=2048, D=1024, H=16, HD=64, M = B*S = 8192.

typedef unsigned short ushortT;
typedef __attribute__((ext_vector_type(8))) __bf16 bf16x8;
typedef __attribute__((ext_vector_type(4))) float f32x4;
typedef __attribute__((ext_vector_type(16))) float f32x16;
typedef __attribute__((ext_vector_type(8))) unsigned short ushort8;
typedef __attribute__((ext_vector_type(4))) unsigned short ushort4v;

__device__ __forceinline__ unsigned short f2bf(float f) {
  union { float f; unsigned u; } x; x.f = f;
  unsigned r = (x.u + 0x7FFFu + ((x.u >> 16) & 1u)) >> 16;  // RNE
  return (unsigned short)r;
}

__device__ __forceinline__ float bf2f(ushortT u) {
  union { unsigned u; float f; } x;
  x.u = ((unsigned)u) << 16;
  return x.f;
}

// packed f32x2 -> bf16x2 (RNE), dst[15:0]=lo, dst[31:16]=hi
__device__ __forceinline__ unsigned cvtpk_bf16(float lo, float hi) {
  unsigned r;
  asm("v_cvt_pk_bf16_f32 %0, %1, %2" : "=v"(r) : "v"(lo), "v"(hi));
  return r;
}

__device__ __forceinline__ void load_lds16(const void* g, void* l) {
  __builtin_amdgcn_global_load_lds(
      (const __attribute__((address_space(1))) void*)g,
      (__attribute__((address_space(3))) void*)l, 16, 0, 0);
}

__device__ __forceinline__ f32x4 mfma16(bf16x8 a, bf16x8 b, f32x4 c) {
  return __builtin_amdgcn_mfma_f32_16x16x32_bf16(a, b, c, 0, 0, 0);
}
__device__ __forceinline__ f32x16 mfma32(bf16x8 a, bf16x8 b, f32x16 c) {
  return __builtin_amdgcn_mfma_f32_32x32x16_bf16(a, b, c, 0, 0, 0);
}

// ---------------- f32 -> bf16 convert, all 6 tensors in one launch ---------
__global__ __launch_bounds__(256) void k_cvt_all(
    const float* __restrict__ x, const float* __restrict__ y,
    const float* __restrict__ w0, const float* __restrict__ w1,
    const float* __restrict__ w2, const float* __restrict__ w3,
    ushortT* __restrict__ ox, ushortT* __restrict__ oy,
    ushortT* __restrict__ o0, ushortT* __restrict__ o1,
    ushortT* __restrict__ o2, ushortT* __restrict__ o3) {
  int b = blockIdx.x;
  const float* in;
  ushortT* out;
  int blk;
  if (b < 4096) {
    in = x; out = ox; blk = b;
  } else if (b < 8192) {
    in = y; out = oy; blk = b - 4096;
  } else {
    int z = (b - 8192) >> 9;
    blk = (b - 8192) & 511;
    in = (z == 0) ? w0 : (z == 1) ? w1 : (z == 2) ? w2 : w3;
    out = (z == 0) ? o0 : (z == 1) ? o1 : (z == 2) ? o2 : o3;
  }
  int i = blk * 256 + threadIdx.x;
  const float4* p = (const float4*)in;
  float4 u = p[(size_t)i * 2];
  float4 v = p[(size_t)i * 2 + 1];
  ushort8 o;
  o[0] = f2bf(u.x); o[1] = f2bf(u.y); o[2] = f2bf(u.z); o[3] = f2bf(u.w);
  o[4] = f2bf(v.x); o[5] = f2bf(v.y); o[6] = f2bf(v.z); o[7] = f2bf(v.w);
  *(ushort8*)(out + (size_t)i * 8) = o;
}

// ---------------- GEMM: C[m,n] = sum_k A[m,k]*W[n,k] (+epilogues) ------
// 512 threads = 8 waves (4x2 wave-grid, 32x64 sub-tile each), 128^2 tile,
// T3-min 2-phase double-buffer: STAGE(next) before compute(cur), ONE
// __syncthreads per K-step. 64KB LDS -> 2 blocks/CU -> 4 waves/SIMD.
// (r10 proven structure; r11-r13 structural experiments all regressed.)
// mode 0: Q = (x@Wq^T + bq) * c1 -> [B,H,S,HD] bf16  (softmax temp prescale)
// mode 1: K = y@Wk^T + bk  -> [B,H,S,HD] bf16
// mode 2: V = x@Wv^T + bv  -> [B,H,HD,S] bf16 (transposed)
// mode 3: H = ctx@Wd^T + bd + xbf -> [M,D] BF16 (halves H write+read traffic)
__global__ __launch_bounds__(512, 4) void k_gemm(
    const ushortT* __restrict__ xbf, const ushortT* __restrict__ ybf,
    const ushortT* __restrict__ wq, const ushortT* __restrict__ wk,
    const ushortT* __restrict__ wv, const ushortT* __restrict__ wd,
    const float* __restrict__ bq, const float* __restrict__ bk,
    const float* __restrict__ bv, const float* __restrict__ bd,
    const ushortT* __restrict__ ctx, const float* __restrict__ xres,
    ushortT* __restrict__ Qo, ushortT* __restrict__ Ko,
    ushortT* __restrict__ Vt, ushortT* __restrict__ Ho, int mode_base) {
  __shared__ ushortT lA[2][128 * 64];
  __shared__ ushortT lB[2][128 * 64];
  const int t = threadIdx.x;
  const int lane = t & 63;
  const int w = t >> 6;            // 0..7
  const int wm = w >> 1, wn = w & 1;  // 4 x 2 wave grid
  const int mode = mode_base + blockIdx.z;
  // T1 XCD y-band swizzle: XCD c gets y in [8c, 8c+8), all 8 x per y.
  const int flat = blockIdx.x + (blockIdx.y << 3);
  const int xcd = flat & 7, j = flat >> 3;
  const int m0 = (xcd * 8 + (j >> 3)) * 128;
  const int n0 = (j & 7) * 128;

  const ushortT* A = (mode == 1) ? ybf : (mode == 3 ? ctx : xbf);
  const ushortT* W = (mode == 0) ? wq : (mode == 1 ? wk : (mode == 2 ? wv : wd));
  const float* bias = (mode == 0) ? bq : (mode == 1 ? bk : (mode == 2 ? bv : bd));

  f32x4 z = {0.f, 0.f, 0.f, 0.f};
  f32x4 acc[2][4];
#pragma unroll
  for (int i = 0; i < 2; ++i)
#pragma unroll
    for (int j2 = 0; j2 < 4; ++j2) acc[i][j2] = z;

  // staging precompute (linear LDS dest; pre-swizzled global source)
  const int so = t * 16;                          // 0..8176
  const int srow = so >> 7;                       // 0..63 (128B per row)
  const int skb = (so & 127) ^ ((srow & 7) << 4); // pre-swizzled source col
  const ushortT* asrc = A + (size_t)(m0 + srow) * 1024 + (skb >> 1);
  const ushortT* wsrc = W + (size_t)(n0 + srow) * 1024 + (skb >> 1);

  // 512 thr x 16B = 8KB per c-iter; c<2 covers the 16KB (128x64 bf16) tile.
#define GSTAGE(buf, k0)                                                     \
  do {                                                                      \
    _Pragma("unroll")                                                       \
    for (int c = 0; c < 2; ++c) {                                           \
      load_lds16(asrc + (k0) + (size_t)c * 64 * 1024,                       \
                 (char*)&lA[buf][0] + c * 8192 + t * 16);                   \
      load_lds16(wsrc + (k0) + (size_t)c * 64 * 1024,                       \
                 (char*)&lB[buf][0] + c * 8192 + t * 16);                   \
    }                                                                       \
  } while (0)

  GSTAGE(0, 0);
  __syncthreads();
  int cur = 0;
  for (int k0 = 0; k0 < 1024; k0 += 64) {
    if (k0 + 64 < 1024) GSTAGE(cur ^ 1, k0 + 64);
#pragma unroll
    for (int kk = 0; kk < 2; ++kk) {
      bf16x8 af[2], bfr[4];
#pragma unroll
      for (int i = 0; i < 2; ++i) {
        int arow = wm * 32 + i * 16 + (lane & 15);
        int ak = ((kk * 32 + (lane >> 4) * 8) * 2) ^ ((arow & 7) << 4);
        af[i] = *(const bf16x8*)((const char*)&lA[cur][0] + arow * 128 + ak);
      }
#pragma unroll
      for (int i = 0; i < 4; ++i) {
        int brow = wn * 64 + i * 16 + (lane & 15);
        int bk2 = ((kk * 32 + (lane >> 4) * 8) * 2) ^ ((brow & 7) << 4);
        bfr[i] = *(const bf16x8*)((const char*)&lB[cur][0] + brow * 128 + bk2);
      }
      __builtin_amdgcn_s_setprio(1);
#pragma unroll
      for (int i = 0; i < 2; ++i)
#pragma unroll
        for (int j2 = 0; j2 < 4; ++j2)
          acc[i][j2] = mfma16(af[i], bfr[j2], acc[i][j2]);
      __builtin_amdgcn_s_setprio(0);
    }
    __syncthreads();
    cur ^= 1;
  }
#undef GSTAGE

  const int cm = wm * 32 + (lane >> 4) * 4;  // + mi*16 + r
  const int cn = wn * 64 + (lane & 15);      // + ni*16
  if (mode == 3) {
#pragma unroll
    for (int mi = 0; mi < 2; ++mi)
#pragma unroll
      for (int ni = 0; ni < 4; ++ni) {
        int n = n0 + cn + ni * 16;
        float bn = bias[n];
#pragma unroll
        for (int r = 0; r < 4; ++r) {
          int m = m0 + cm + mi * 16 + r;
          Ho[(size_t)m * 1024 + n] =
              f2bf(acc[mi][ni][r] + bn + bf2f(xbf[(size_t)m * 1024 + n]));
        }
      }
  } else if (mode == 2) {
#pragma unroll
    for (int mi = 0; mi < 2; ++mi)
#pragma unroll
      for (int ni = 0; ni < 4; ++ni) {
        int n = n0 + cn + ni * 16;
        int hh = n >> 6, hd = n & 63;
        float bn = bias[n];
        int m_ = m0 + cm + mi * 16;
        int b = m_ >> 11, s = m_ & 2047;
        ushort4v pk;
#pragma unroll
        for (int r = 0; r < 4; ++r) pk[r] = f2bf(acc[mi][ni][r] + bn);
        *(ushort4v*)&Vt[(((size_t)(b * 16 + hh) * 64 + hd) << 11) + s] = pk;
      }
  } else {
    ushortT* O = (mode == 0) ? Qo : Ko;
    // mode 0: fold softmax temperature (1/8)*log2(e) into Q so the attention
    // kernel computes p = exp2(sc) with no per-score multiply.
    const float qs = (mode == 0) ? 0.18033688011112042f : 1.0f;
#pragma unroll
    for (int mi = 0; mi < 2; ++mi)
#pragma unroll
      for (int ni = 0; ni < 4; ++ni) {
        int n = n0 + cn + ni * 16;
        int hh = n >> 6, hd = n & 63;
        float bn = bias[n];
#pragma unroll
        for (int r = 0; r < 4; ++r) {
          int m = m0 + cm + mi * 16 + r;
          int b = m >> 11, s = m & 2047;
          O[(((size_t)(b * 16 + hh) * 2048 + s) << 6) + hd] =
              f2bf((acc[mi][ni][r] + bn) * qs);
        }
      }
  }
}

// ---------------- Flash attention, 4-wave swapped-QK^T 32x32 ----------------
// grid: 1024 blocks (16 qtiles x 64 bh), XCD-swizzled; block 256 = 4 waves.
// Each wave owns 32 q-rows; KV tile = 64 keys, double-buffered in LDS.
// Q prescaled by (1/8)*log2(e) in k_gemm -> p = exp2(sc) raw.
// Row-sums via MFMA with ones-B: accL[r] = sum_k P[k][q=qm(r,hi)].
__global__ __launch_bounds__(256, 4) void k_attn(const ushortT* __restrict__ Q,
                                                 const ushortT* __restrict__ K,
                                                 const ushortT* __restrict__ Vt,
                                                 ushortT* __restrict__ ctx) {
  __shared__ ushortT lK[2][4096];  // [buf][64 keys][64 d], 128B rows, XOR-swz
  __shared__ ushortT lV[2][4096];  // [buf][64 d][64 keys], 128B rows, XOR-swz
  const int t = threadIdx.x, lane = t & 63, w = t >> 6;
  const int hi = lane >> 5, l31 = lane & 31;
  const int i0 = blockIdx.x;
  const int xcd = i0 & 7, j0 = i0 >> 3;              // round-robin XCD map
  const int bh = xcd * 8 + (j0 >> 4);                // 8 bh per XCD -> L2-fit
  const int qt = j0 & 15;
  const int q0 = qt * 128 + w * 32;

  const ushortT* Qb = Q + ((size_t)bh * 2048 + q0) * 64;
  const ushortT* Kb = K + (size_t)bh * 2048 * 64;
  const ushortT* Vb = Vt + (size_t)bh * 64 * 2048;

  // Q fragments (B-operand): Q[q=l31, d = dc*16 + hi*8 + j]
  bf16x8 qf[4];
#pragma unroll
  for (int dc = 0; dc < 4; ++dc)
    qf[dc] = *(const bf16x8*)(Qb + l31 * 64 + dc * 16 + hi * 8);

  // ones B-operand for row-sum MFMA
  union { unsigned short us[8]; bf16x8 v; } ones_u;
#pragma unroll
  for (int i = 0; i < 8; ++i) ones_u.us[i] = 0x3F80;

  f32x16 accO0, accO1, accL;
#pragma unroll
  for (int i = 0; i < 16; ++i) { accO0[i] = 0.f; accO1[i] = 0.f; accL[i] = 0.f; }

  // staging: linear LDS dest, pre-swizzled global source (rule #21)
  const int srow = t >> 3;                 // 0..31
  const int scolb = ((t & 7) * 16) ^ ((srow & 7) << 4);
  const ushortT* ksrc = Kb + srow * 64 + (scolb >> 1);
  const ushortT* vsrc = Vb + (size_t)srow * 2048 + (scolb >> 1);
  const int swz = (lane & 7) << 4;
  const int hs = (hi * 16) ^ swz;
  const int krowb = l31 * 128;

#define STAGE(buf, kk)                                                        \
  do {                                                                        \
    load_lds16(ksrc + (size_t)(kk) * 64, (char*)&lK[buf][0] + w * 1024);      \
    load_lds16(ksrc + 2048 + (size_t)(kk) * 64,                               \
               (char*)&lK[buf][0] + 4096 + w * 1024);                         \
    load_lds16(vsrc + (kk), (char*)&lV[buf][0] + w * 1024);                   \
    load_lds16(vsrc + 65536 + (kk), (char*)&lV[buf][0] + 4096 + w * 1024);    \
  } while (0)

  STAGE(0, 0);
  __syncthreads();
  int cur = 0;
  for (int k0 = 0; k0 < 2048; k0 += 64) {
    if (k0 + 64 < 2048) STAGE(cur ^ 1, k0 + 64);
    const char* lKc = (const char*)&lK[cur][0];
    const char* lVc = (const char*)&lV[cur][0];
#pragma unroll
    for (int kb = 0; kb < 2; ++kb) {
      // ---- QK^T (swapped): sc[r] = S[krow(r,hi), q=l31]
      f32x16 sc;
#pragma unroll
      for (int i = 0; i < 16; ++i) sc[i] = 0.f;
      __builtin_amdgcn_s_setprio(1);
#pragma unroll
      for (int dc = 0; dc < 4; ++dc) {
        bf16x8 kf = *(const bf16x8*)(lKc + kb * 4096 + krowb + ((dc * 32) ^ hs));
        sc = mfma32(kf, qf[dc], sc);
      }
      __builtin_amdgcn_s_setprio(0);
      // ---- softmax numerator: p = exp2(sc) (raw v_exp_f32, no ocml fixup)
      float p[16];
#pragma unroll
      for (int r = 0; r < 16; ++r) p[r] = __builtin_amdgcn_exp2f(sc[r]);
      // ---- pack P -> bf16 words (cvt_pk); exchange halves (permlane32_swap)
      union { unsigned u[4]; bf16x8 v; } pa0, pa1;
#pragma unroll
      for (int i = 0; i < 4; ++i) {
        int base = (i >> 1) * 8 + (i & 1) * 2;  // 0,2,8,10
        unsigned a = cvtpk_bf16(p[base], p[base + 1]);        // keys 4hi+b..
        unsigned b = cvtpk_bf16(p[base + 4], p[base + 5]);    // keys 8+4hi+b..
        asm("v_permlane32_swap_b32 %0, %1" : "+v"(a), "+v"(b));
        if (i >> 1) { pa1.u[i & 1] = a; pa1.u[2 + (i & 1)] = b; }
        else        { pa0.u[i & 1] = a; pa0.u[2 + (i & 1)] = b; }
      }
      // ---- PV + row-sum: accO[nb] += P x V ; accL += P x ones
      __builtin_amdgcn_s_setprio(1);
#pragma unroll
      for (int nb = 0; nb < 2; ++nb) {
        const char* vrow = lVc + (nb * 32 + l31) * 128;
        bf16x8 vf0 = *(const bf16x8*)(vrow + ((kb * 64) ^ hs));
        bf16x8 vf1 = *(const bf16x8*)(vrow + ((kb * 64 + 32) ^ hs));
        f32x16& ao = nb ? accO1 : accO0;
        ao = mfma32(pa0.v, vf0, ao);
        ao = mfma32(pa1.v, vf1, ao);
      }
      accL = mfma32(pa0.v, ones_u.v, accL);
      accL = mfma32(pa1.v, ones_u.v, accL);
      __builtin_amdgcn_s_setprio(0);
    }
    __syncthreads();
    cur ^= 1;
  }
#undef STAGE

  // epilogue: O[q,d] = accO/accL -> ctx[B,S,D] bf16
  int b = bh >> 4, hh = bh & 15;
  ushortT* cb = ctx + ((size_t)(b * 2048 + q0)) * 1024 + hh * 64;
#pragma unroll
  for (int r = 0; r < 16; ++r) {
    int qm = (r & 3) + 8 * (r >> 2) + 4 * hi;
    float lr = 1.0f / accL[r];
    size_t rb = (size_t)qm * 1024;
    cb[rb + l31] = f2bf(accO0[r] * lr);
    cb[rb + 32 + l31] = f2bf(accO1[r] * lr);
  }
}

// ---------------- LayerNorm (one row per block, bf16 input) ----------------
__global__ __launch_bounds__(256) void k_ln(const ushortT* __restrict__ Hi,
                                            const float* __restrict__ gamma,
                                            const float* __restrict__ beta,
                                            float* __restrict__ out) {
  const int row = blockIdx.x, t = threadIdx.x, lane = t & 63, w = t >> 6;
  ushort4v hv = *(const ushort4v*)(Hi + (size_t)row * 1024 + t * 4);
  float4 v;
  v.x = bf2f(hv[0]); v.y = bf2f(hv[1]); v.z = bf2f(hv[2]); v.w = bf2f(hv[3]);
  float s1 = v.x + v.y + v.z + v.w;
  float s2 = v.x * v.x + v.y * v.y + v.z * v.z + v.w * v.w;
#pragma unroll
  for (int off = 1; off < 64; off <<= 1) {
    s1 += __shfl_xor(s1, off);
    s2 += __shfl_xor(s2, off);
  }
  __shared__ float red[8];
  if (lane == 0) { red[w] = s1; red[4 + w] = s2; }
  __syncthreads();
  s1 = red[0] + red[1] + red[2] + red[3];
  s2 = red[4] + red[5] + red[6] + red[7];
  float u = s1 * (1.f / 1024.f);
  float var = s2 * (1.f / 1024.f) - u * u;
  float rstd = rsqrtf(var + 1e-12f);
  float4 g = ((const float4*)gamma)[t];
  float4 bb = ((const float4*)beta)[t];
  float4 oo;
  oo.x = (v.x - u) * rstd * g.x + bb.x;
  oo.y = (v.y - u) * rstd * g.y + bb.y;
  oo.z = (v.z - u) * rstd * g.z + bb.z;
  oo.w = (v.w - u) * rstd * g.w + bb.w;
  ((float4*)(out + (size_t)row * 1024))[t] = oo;
}

extern "C" void kernel_launch(void* const* d_in, const int* in_sizes, int n_in,
                              void* d_out, int out_size, void* d_ws,
                              size_t ws_size, hipStream_t stream) {
  const float* x = (const float*)d_in[0];
  const float* y = (const float*)d_in[1];
  const float* Wq = (const float*)d_in[2];
  const float* bq = (const float*)d_in[3];
  const float* Wk = (const float*)d_in[4];
  const float* bk = (const float*)d_in[5];
  const float* Wv = (const float*)d_in[6];
  const float* bv = (const float*)d_in[7];
  const float* Wd = (const float*)d_in[8];
  const float* bd = (const float*)d_in[9];
  const float* gamma = (const float*)d_in[10];
  const float* beta = (const float*)d_in[11];

  char* ws = (char*)d_ws;
  ushortT* xbf = (ushortT*)(ws + 0);          // 16 MiB
  ushortT* ybf = (ushortT*)(ws + 16777216);   // 16 MiB
  ushortT* wqb = (ushortT*)(ws + 33554432);   // 2 MiB
  ushortT* wkb = (ushortT*)(ws + 35651584);
  ushortT* wvb = (ushortT*)(ws + 37748736);
  ushortT* wdb = (ushortT*)(ws + 39845888);
  ushortT* Qb = (ushortT*)(ws + 41943040);    // 16 MiB
  ushortT* Kb = (ushortT*)(ws + 58720256);    // 16 MiB
  ushortT* Vtb = (ushortT*)(ws + 75497472);   // 16 MiB
  ushortT* ctx = (ushortT*)(ws + 92274688);   // 16 MiB
  ushortT* Hbf = (ushortT*)(ws + 109051904);  // 16 MiB (bf16 H)

  k_cvt_all<<<10240, 256, 0, stream>>>(x, y, Wq, Wk, Wv, Wd, xbf, ybf, wqb,
                                       wkb, wvb, wdb);

  k_gemm<<<dim3(8, 64, 3), 512, 0, stream>>>(xbf, ybf, wqb, wkb, wvb, wdb, bq,
                                             bk, bv, bd, ctx, x, Qb, Kb, Vtb,
                                             Hbf, 0);
  k_attn<<<1024, 256, 0, stream>>>(Qb, Kb, Vtb, ctx);
  k_gemm<<<dim3(8, 64, 1), 512, 0, stream>>>(xbf, ybf, wqb, wkb, wvb, wdb, bq,
                                             bk, bv, bd, ctx, x, Qb, Kb, Vtb,
                                             Hbf, 3);
  k_ln<<<8192, 256, 0, stream>>>(Hbf, gamma, beta, (float*)d_out);
}